// Round 6
// baseline (1251.169 us; speedup 1.0000x reference)
//
#include <hip/hip_runtime.h>

namespace {

constexpr int Bn = 2;
constexpr int Dn = 64;
constexpr int Hn = 96;
constexpr int Wn = 96;
constexpr int HW = Hn * Wn;          // 9216
constexpr int S  = Dn * HW;          // 589824 per (vol,batch) slab
constexpr int NBS = Bn * S;          // 1179648
constexpr int NT  = 2 * NBS;         // 2359296 (slabs: predB0,predB1,truthB0,truthB1)
constexpr int WPR = Wn / 32;         // 3 words per x-row
constexpr int WPP = HW / 32;         // 288 words per z-plane
constexpr int WPS = S / 32;          // 18432 words per slab
constexpr int NTW = NT / 32;         // 73728 packed words
constexpr float INFD = 1e12f;
constexpr float EPSf = 1e-7f;
constexpr int TPB = 256;
constexpr int GRID_NB = 1024;        // 4 blocks/CU x 256 CUs -- all co-resident
constexpr int OPT = 8;               // EDT outputs per thread
constexpr int ITEMS = 288;           // work items per block in EDT/sums phases

// ---------------- grid barrier (one-shot counter per sync) ----------------
__device__ __forceinline__ void gsync(unsigned* bar, int bid) {
  __syncthreads();
  if (threadIdx.x == 0) {
    __threadfence();                                   // release our writes
    __hip_atomic_fetch_add(&bar[bid], 1u, __ATOMIC_ACQ_REL, __HIP_MEMORY_SCOPE_AGENT);
    while (__hip_atomic_load(&bar[bid], __ATOMIC_ACQUIRE, __HIP_MEMORY_SCOPE_AGENT)
           != (unsigned)GRID_NB) {
      __builtin_amdgcn_s_sleep(2);
    }
    __threadfence();                                   // acquire others' writes
  }
  __syncthreads();
}

// erode one word of a tiled LDS array; row stride 3, plane stride ps.
// Halo rows/planes hold 1s (erode pad); x edges pad via wx checks.
__device__ __forceinline__ unsigned erode_t(const unsigned* A, int idx, int ps, int wx) {
  unsigned v = A[idx];
  unsigned l = (v << 1) | (wx > 0 ? (A[idx - 1] >> 31) : 1u);
  unsigned r = (v >> 1) | (wx < 2 ? (A[idx + 1] << 31) : 0x80000000u);
  unsigned ym = A[idx - 3];
  unsigned yp = A[idx + 3];
  unsigned zm = A[idx - ps];
  unsigned zp = A[idx + ps];
  return v & l & r & ym & yp & zm & zp;
}

// ---- skeleton group: NUP chained updates on a 24-row y-tile of one plane ----
// From X: E=erode(X) [,E2=erode(E)]; skel (|)= (X&~dil3(E)) [ | (E&~dil3(E2)) ];
// next X = E (NUP=1) or E2 (NUP=2). OOB halos loaded as 1s: computed OOB-row/plane
// values are supersets of in-bounds erosions -> neutral under AND (verified R5).
template <int NUP>
__device__ void skel_group(const unsigned* __restrict__ x, unsigned* __restrict__ eout,
                           unsigned* __restrict__ skel, bool init, unsigned* shm) {
  constexpr int XH = NUP + 1;
  constexpr int XPL = 2 * XH + 1;
  constexpr int XRW = 24 + 2 * XH;
  constexpr int PSX = XRW * 3;
  constexpr int EPL = 2 * NUP + 1;
  constexpr int ERW = 24 + 2 * NUP;
  constexpr int PSE = ERW * 3;
  constexpr int PSE2 = 26 * 3;                   // NUP==2 only: 3 planes x 26 rows
  unsigned* lx = shm;
  unsigned* le = shm + XPL * PSX;
  unsigned* le2 = le + EPL * PSE;
  int task = blockIdx.x;                          // 1024 tasks: slab(4) x z(64) x ytile(4)
  int slab = task >> 8;
  int z = (task >> 2) & 63;
  int y0 = (task & 3) * 24;
  int tid = threadIdx.x;
  const unsigned* xs = x + slab * WPS;
  for (int t = tid; t < XPL * PSX; t += TPB) {
    int p = t / PSX; int rem = t - p * PSX; int r = rem / 3; int wx = rem - r * 3;
    int zz = z - XH + p, yy = y0 - XH + r;
    lx[t] = (zz >= 0 && zz < Dn && yy >= 0 && yy < Hn)
              ? xs[zz * WPP + yy * WPR + wx] : 0xFFFFFFFFu;
  }
  __syncthreads();
  for (int t = tid; t < EPL * PSE; t += TPB) {
    int p = t / PSE; int rem = t - p * PSE; int r = rem / 3; int wx = rem - r * 3;
    le[t] = erode_t(lx, (p + 1) * PSX + (r + 1) * 3 + wx, PSX, wx);
  }
  __syncthreads();
  if constexpr (NUP == 2) {
    for (int t = tid; t < 3 * PSE2; t += TPB) {
      int p = t / PSE2; int rem = t - p * PSE2; int r = rem / 3; int wx = rem - r * 3;
      le2[t] = erode_t(le, (p + 1) * PSE + (r + 1) * 3 + wx, PSE, wx);
    }
    __syncthreads();
  }
  for (int t = tid; t < 72; t += TPB) {           // 24 rows x 3 words
    int r = t / 3, wx = t - r * 3;
    int yy = y0 + r;
    unsigned accE = 0u;
    #pragma unroll
    for (int dz = -1; dz <= 1; ++dz) {
      if (z + dz < 0 || z + dz >= Dn) continue;
      #pragma unroll
      for (int dy = -1; dy <= 1; ++dy) {
        if (yy + dy < 0 || yy + dy >= Hn) continue;
        int ii = (dz + NUP) * PSE + (r + dy + NUP) * 3 + wx;
        unsigned c = le[ii];
        unsigned pw = (wx > 0) ? le[ii - 1] : 0u;
        unsigned nw = (wx < 2) ? le[ii + 1] : 0u;
        accE |= c | ((c << 1) | (pw >> 31)) | ((c >> 1) | (nw << 31));
      }
    }
    unsigned xv = lx[XH * PSX + (r + XH) * 3 + wx];
    unsigned sk = xv & ~accE;
    unsigned ex;
    if constexpr (NUP == 2) {
      unsigned accE2 = 0u;
      #pragma unroll
      for (int dz = -1; dz <= 1; ++dz) {
        if (z + dz < 0 || z + dz >= Dn) continue;
        #pragma unroll
        for (int dy = -1; dy <= 1; ++dy) {
          if (yy + dy < 0 || yy + dy >= Hn) continue;
          int ii = (dz + 1) * PSE2 + (r + dy + 1) * 3 + wx;
          unsigned c = le2[ii];
          unsigned pw = (wx > 0) ? le2[ii - 1] : 0u;
          unsigned nw = (wx < 2) ? le2[ii + 1] : 0u;
          accE2 |= c | ((c << 1) | (pw >> 31)) | ((c >> 1) | (nw << 31));
        }
      }
      unsigned ev = le[NUP * PSE + (r + NUP) * 3 + wx];
      sk |= ev & ~accE2;
      ex = le2[PSE2 + (r + 1) * 3 + wx];
    } else {
      ex = le[NUP * PSE + (r + NUP) * 3 + wx];
    }
    int gi = slab * WPS + z * WPP + yy * WPR + wx;
    eout[gi] = ex;
    skel[gi] = init ? sk : (skel[gi] | sk);
  }
}

// ---------------- init: zero the barrier slots ----------------
__global__ __launch_bounds__(64) void k_init(unsigned* bar) {
  if (threadIdx.x < 16) bar[threadIdx.x] = 0u;
}

// ---------------- the megakernel ----------------
__global__ __launch_bounds__(TPB, 4) void k_mega(
    const float* __restrict__ logits, const int* __restrict__ labels,
    float* __restrict__ D2, float* __restrict__ EF,
    unsigned* __restrict__ MB, unsigned* __restrict__ XB,
    unsigned* __restrict__ EB, unsigned* __restrict__ SKELB,
    float* __restrict__ PMAX, double* __restrict__ PS,
    float* __restrict__ RMAXF, unsigned* __restrict__ bar,
    float* __restrict__ out) {
  __shared__ unsigned shm[1284];                 // skeleton tiles (NUP=2 worst case)
  __shared__ double ldsd[4][4];
  __shared__ float ldsf[4];
  int tid = threadIdx.x;
  int gtid = blockIdx.x * TPB + tid;

  // ---- phase 1: binarize (bit-pack via ballot) ----
  for (int idx = gtid; idx < NBS; idx += GRID_NB * TPB) {
    int b = idx / S;
    int s = idx - b * S;
    float l0 = logits[(b * 2 + 0) * S + s];
    float l1 = logits[(b * 2 + 1) * S + s];
    bool vp = l1 > l0;
    bool vt = labels[idx] > 0;
    unsigned long long mp = __ballot(vp);
    unsigned long long mt = __ballot(vt);
    int lane = tid & 63;
    if (lane == 0) {
      MB[idx >> 5]         = (unsigned)mp;
      MB[(NBS + idx) >> 5] = (unsigned)mt;
    } else if (lane == 32) {
      MB[idx >> 5]         = (unsigned)(mp >> 32);
      MB[(NBS + idx) >> 5] = (unsigned)(mt >> 32);
    }
  }
  gsync(bar, 0);

  // ---- phase 2: skeleton, 11 updates = 5x NUP2 + 1x NUP1 ----
  skel_group<2>(MB, XB, SKELB, true, shm);  gsync(bar, 1);
  skel_group<2>(XB, EB, SKELB, false, shm); gsync(bar, 2);
  skel_group<2>(EB, XB, SKELB, false, shm); gsync(bar, 3);
  skel_group<2>(XB, EB, SKELB, false, shm); gsync(bar, 4);
  skel_group<2>(EB, XB, SKELB, false, shm); gsync(bar, 5);
  skel_group<1>(XB, EB, SKELB, false, shm);
  // no sync needed before edt0 (reads only MB); skel writes drain by bar 6/7.

  // ---- phase 3: EDT pass 0 (z axis, L=64) from mask bits ----
  for (int t = tid; t < ITEMS; t += TPB) {
    int item = blockIdx.x * ITEMS + t;
    int chunk = item / (4 * HW);
    int c = item - chunk * (4 * HW);
    int slab = c / HW;
    int s2d = c - slab * HW;
    int i0 = chunk * OPT;
    const unsigned* mb = MB + slab * WPS;
    float best[OPT];
    #pragma unroll
    for (int s = 0; s < OPT; ++s) best[s] = 3.4e38f;
    float db = (float)i0;
    #pragma unroll 4
    for (int j = 0; j < Dn; ++j) {
      int bi = j * HW + s2d;
      float f = ((mb[bi >> 5] >> (bi & 31)) & 1u) ? INFD : 0.0f;
      #pragma unroll
      for (int s = 0; s < OPT; ++s) {
        float d = db + (float)s;
        best[s] = fminf(best[s], fmaf(d, d, f));
      }
      db -= 1.0f;
    }
    float* o = D2 + slab * S + s2d;
    #pragma unroll
    for (int s = 0; s < OPT; ++s) o[(i0 + s) * HW] = best[s];
  }
  gsync(bar, 6);

  // ---- phase 4: EDT pass 1 (y axis, L=96) ----
  for (int t = tid; t < ITEMS; t += TPB) {
    int item = blockIdx.x * ITEMS + t;
    int chunk = item / (4 * Dn * Wn);
    int cc = item - chunk * (4 * Dn * Wn);
    int sz = cc / Wn;
    int x = cc - sz * Wn;
    int base = sz * HW + x;
    int i0 = chunk * OPT;
    float best[OPT];
    #pragma unroll
    for (int s = 0; s < OPT; ++s) best[s] = 3.4e38f;
    float db = (float)i0;
    #pragma unroll 4
    for (int j = 0; j < Hn; ++j) {
      float f = D2[base + j * Wn];
      #pragma unroll
      for (int s = 0; s < OPT; ++s) {
        float d = db + (float)s;
        best[s] = fminf(best[s], fmaf(d, d, f));
      }
      db -= 1.0f;
    }
    #pragma unroll
    for (int s = 0; s < OPT; ++s) EF[base + (i0 + s) * Wn] = best[s];
  }
  gsync(bar, 7);

  // ---- phase 5: EDT pass 2 (x axis) + skel-masked per-block max of d2 ----
  {
    float m = 0.0f;
    for (int t = tid; t < ITEMS; t += TPB) {
      int item = blockIdx.x * ITEMS + t;
      int row = item / 12;
      int chunk = item - row * 12;
      int base = row * Wn;
      int i0 = chunk * OPT;
      float best[OPT];
      #pragma unroll
      for (int s = 0; s < OPT; ++s) best[s] = 3.4e38f;
      float db = (float)i0;
      #pragma unroll 4
      for (int j = 0; j < Wn; ++j) {
        float f = EF[base + j];
        #pragma unroll
        for (int s = 0; s < OPT; ++s) {
          float d = db + (float)s;
          best[s] = fminf(best[s], fmaf(d, d, f));
        }
        db -= 1.0f;
      }
      #pragma unroll
      for (int s = 0; s < OPT; ++s) D2[base + i0 + s] = best[s];
      unsigned wv = SKELB[(base + i0) >> 5] >> (i0 & 31);
      #pragma unroll
      for (int s = 0; s < OPT; ++s)
        if ((wv >> s) & 1u) m = fmaxf(m, best[s]);
    }
    #pragma unroll
    for (int o = 32; o > 0; o >>= 1) m = fmaxf(m, __shfl_xor(m, o, 64));
    if ((tid & 63) == 0) ldsf[tid >> 6] = m;
    __syncthreads();
    if (tid == 0)
      PMAX[blockIdx.x] = fmaxf(fmaxf(ldsf[0], ldsf[1]), fmaxf(ldsf[2], ldsf[3]));
  }
  gsync(bar, 8);

  // ---- phase 6: per-slab rmax (blocks 0..3), sqrt deferred to here ----
  if (blockIdx.x < 4) {
    float m = PMAX[blockIdx.x * 256 + tid];
    #pragma unroll
    for (int o = 32; o > 0; o >>= 1) m = fmaxf(m, __shfl_xor(m, o, 64));
    if ((tid & 63) == 0) ldsf[tid >> 6] = m;
    __syncthreads();
    if (tid == 0)
      RMAXF[blockIdx.x] = sqrtf(fmaxf(fmaxf(ldsf[0], ldsf[1]), fmaxf(ldsf[2], ldsf[3])));
  }
  gsync(bar, 9);

  // ---- phase 7: weighted sums (4 voxels per item, float4 loads) ----
  {
    double acc[4] = {0.0, 0.0, 0.0, 0.0};
    for (int t = tid; t < ITEMS; t += TPB) {
      int q = blockIdx.x * ITEMS + t;                // quad over NBS/4
      int idx0 = q * 4;
      int b = idx0 / S;
      float rmax_p = RMAXF[b];
      float rmax_t = RMAXF[2 + b];
      float4 dp4 = ((const float4*)D2)[q];
      float4 dt4 = ((const float4*)(D2 + NBS))[q];
      unsigned spw = (SKELB[idx0 >> 5] >> (idx0 & 31)) & 0xFu;
      unsigned stw = (SKELB[(NBS + idx0) >> 5] >> (idx0 & 31)) & 0xFu;
      const float* dp = &dp4.x;
      const float* dt = &dt4.x;
      #pragma unroll
      for (int s = 0; s < 4; ++s) {
        float dist_p = sqrtf(dp[s]);
        float dist_t = sqrtf(dt[s]);
        bool sp = (spw >> s) & 1u;
        bool st = (stw >> s) & 1u;
        float q_vp = (rmax_p > 0.0f) ? dist_p / rmax_p : dist_p;
        float q_vl = (rmax_t > 0.0f) ? dist_t / rmax_t : dist_t;
        float q_spvp = sp ? q_vp : 0.0f;
        float q_slvl = st ? q_vl : 0.0f;
        float q_sp = sp ? (1.0f + EPSf) / (q_spvp * q_spvp + EPSf) : 0.0f;
        float q_sl = st ? (1.0f + EPSf) / (q_slvl * q_slvl + EPSf) : 0.0f;
        acc[0] += (double)(q_sp * q_vl);
        acc[1] += (double)(((q_spvp != 0.0f) && (q_slvl == 0.0f)) ? q_spvp * q_sp
                                                                  : q_slvl * q_sp);
        acc[2] += (double)(q_sl * q_vp);
        acc[3] += (double)(((q_slvl != 0.0f) && (q_spvp == 0.0f)) ? q_slvl * q_sl
                                                                  : q_spvp * q_sl);
      }
    }
    #pragma unroll
    for (int k = 0; k < 4; ++k)
      #pragma unroll
      for (int o = 32; o > 0; o >>= 1)
        acc[k] += __shfl_xor(acc[k], o, 64);
    if ((tid & 63) == 0) {
      #pragma unroll
      for (int k = 0; k < 4; ++k) ldsd[tid >> 6][k] = acc[k];
    }
    __syncthreads();
    if (tid == 0) {
      #pragma unroll
      for (int k = 0; k < 4; ++k)
        PS[blockIdx.x * 4 + k] = ldsd[0][k] + ldsd[1][k] + ldsd[2][k] + ldsd[3][k];
    }
  }
  gsync(bar, 10);

  // ---- phase 8: final reduce + loss (block 0) ----
  if (blockIdx.x == 0) {
    double s[4] = {0.0, 0.0, 0.0, 0.0};
    for (int i = tid; i < GRID_NB; i += TPB) {
      s[0] += PS[i * 4 + 0];
      s[1] += PS[i * 4 + 1];
      s[2] += PS[i * 4 + 2];
      s[3] += PS[i * 4 + 3];
    }
    #pragma unroll
    for (int k = 0; k < 4; ++k)
      #pragma unroll
      for (int o = 32; o > 0; o >>= 1)
        s[k] += __shfl_xor(s[k], o, 64);
    if ((tid & 63) == 0) {
      #pragma unroll
      for (int k = 0; k < 4; ++k) ldsd[tid >> 6][k] = s[k];
    }
    __syncthreads();
    if (tid == 0) {
      double tot[4];
      #pragma unroll
      for (int k = 0; k < 4; ++k)
        tot[k] = ldsd[0][k] + ldsd[1][k] + ldsd[2][k] + ldsd[3][k];
      double wp = (tot[0] + 1.0) / (tot[1] + 1.0);
      double ws = (tot[2] + 1.0) / (tot[3] + 1.0);
      out[0] = (float)(1.0 - 2.0 * (wp * ws) / (wp + ws));
    }
  }
}

} // namespace

extern "C" void kernel_launch(void* const* d_in, const int* in_sizes, int n_in,
                              void* d_out, int out_size, void* d_ws, size_t ws_size,
                              hipStream_t stream) {
  (void)in_sizes; (void)n_in; (void)out_size; (void)ws_size;
  const float* logits = (const float*)d_in[0];   // [B,2,D,H,W] f32
  const int* labels   = (const int*)d_in[1];     // [B,1,D,H,W] i32
  float* out = (float*)d_out;

  float* D2 = (float*)d_ws;                  // EDT ping / final d2
  float* EF = D2 + NT;                       // EDT pong
  unsigned* MB    = (unsigned*)(EF + NT);    // pristine masks
  unsigned* XB    = MB + NTW;
  unsigned* EB    = XB + NTW;
  unsigned* SKELB = EB + NTW;
  float* PMAX  = (float*)(SKELB + NTW);      // 1024
  double* PS   = (double*)(PMAX + GRID_NB);  // 1024x4 (8B-aligned offset)
  float* RMAXF = (float*)(PS + 4 * GRID_NB); // 4
  unsigned* BAR = (unsigned*)(RMAXF + 4);    // 16 barrier slots

  k_init<<<1, 64, 0, stream>>>(BAR);
  k_mega<<<GRID_NB, TPB, 0, stream>>>(logits, labels, D2, EF, MB, XB, EB, SKELB,
                                      PMAX, PS, RMAXF, BAR, out);
}

// Round 8
// 226.009 us; speedup vs baseline: 5.5359x; 5.5359x over previous
//
#include <hip/hip_runtime.h>

namespace {

constexpr int Bn = 2;
constexpr int Dn = 64;
constexpr int Hn = 96;
constexpr int Wn = 96;
constexpr int HW = Hn * Wn;          // 9216
constexpr int S  = Dn * HW;          // 589824 per (vol,batch) slab
constexpr int NBS = Bn * S;          // 1179648
constexpr int NT  = 2 * NBS;         // 2359296 (slabs: predB0,predB1,truthB0,truthB1)
constexpr int WPR = Wn / 32;         // 3 words per x-row
constexpr int WPP = HW / 32;         // 288 words per z-plane
constexpr int WPS = S / 32;          // 18432 words per slab
constexpr int NTW = NT / 32;         // 73728 packed words
constexpr float INFD = 1e12f;
constexpr float EPSf = 1e-7f;
constexpr int TPB = 256;
constexpr int BLK_NBS = NBS / TPB;   // 4608
constexpr int OPT = 8;               // EDT outputs per thread
constexpr int BLK_EDT0 = NT / OPT / TPB;  // 1152
constexpr int BLK_SUMS = NBS / 4 / TPB;   // 1152 (one quad per thread)

// ---- binarize both masks (bit-packed via ballot); zero the DONE ticket ----
__global__ __launch_bounds__(TPB) void k_binarize(const float* __restrict__ logits,
                                                  const int* __restrict__ labels,
                                                  unsigned* __restrict__ Mb,
                                                  unsigned* __restrict__ done) {
  if (blockIdx.x == 0 && threadIdx.x == 0) done[0] = 0u;
  int idx = blockIdx.x * TPB + threadIdx.x;     // over NBS
  int b = idx / S;
  int s = idx - b * S;
  float l0 = logits[(b * 2 + 0) * S + s];
  float l1 = logits[(b * 2 + 1) * S + s];
  bool vp = l1 > l0;                            // softmax(p1)>0.5 <=> l1>l0
  bool vt = labels[idx] > 0;
  unsigned long long mp = __ballot(vp);
  unsigned long long mt = __ballot(vt);
  int lane = threadIdx.x & 63;
  if (lane == 0) {
    Mb[idx >> 5]         = (unsigned)mp;
    Mb[(NBS + idx) >> 5] = (unsigned)mt;
  } else if (lane == 32) {
    Mb[idx >> 5]         = (unsigned)(mp >> 32);
    Mb[(NBS + idx) >> 5] = (unsigned)(mt >> 32);
  }
}

// erode one word; full-plane layout, plane stride WPP; y/x OOB pad = 1s
__device__ __forceinline__ unsigned erode_w(const unsigned* A, int pb, int w,
                                            int y, int wx) {
  unsigned v = A[pb + w];
  unsigned l = (v << 1) | (wx > 0       ? (A[pb + w - 1] >> 31) : 1u);
  unsigned r = (v >> 1) | (wx < WPR - 1 ? (A[pb + w + 1] << 31) : 0x80000000u);
  unsigned ym = (y > 0)      ? A[pb + w - WPR] : 0xFFFFFFFFu;
  unsigned yp = (y < Hn - 1) ? A[pb + w + WPR] : 0xFFFFFFFFu;
  unsigned zm = A[pb - WPP + w];
  unsigned zp = A[pb + WPP + w];
  return v & l & r & ym & yp & zm & zp;
}

// 3x3x3 dilate one word; center plane index pc; logical z-OOB skipped (pad=0)
__device__ __forceinline__ unsigned dil3_w(const unsigned* A, int pc, int z,
                                           int w, int y, int wx) {
  unsigned acc = 0u;
  #pragma unroll
  for (int dz = -1; dz <= 1; ++dz) {
    if (z + dz < 0 || z + dz >= Dn) continue;
    int base = (pc + dz) * WPP + w;
    #pragma unroll
    for (int dy = -1; dy <= 1; ++dy) {
      if (y + dy < 0 || y + dy >= Hn) continue;
      int bb = base + dy * WPR;
      unsigned c = A[bb];
      unsigned p = (wx > 0)       ? A[bb - 1] : 0u;
      unsigned n = (wx < WPR - 1) ? A[bb + 1] : 0u;
      acc |= c | ((c << 1) | (p >> 31)) | ((c >> 1) | (n << 31));
    }
  }
  return acc;
}

// ---- NUP chained skeleton updates per launch, one z-plane per block ----
// Level 0 = X (loaded, z-OOB halo = 1s); level k = erode(level k-1).
// skel (|)= OR_k [ center(L_{k-1}) & ~dil3(L_k) ];  eout = center(L_NUP).
// OOB-computed halo planes are supersets of true pad -> absorbed under AND
// (monotonicity induction; NUP=2 case verified end-to-end in R5/R6).
template <int NUP>
__global__ __launch_bounds__(TPB) void k_skel(const unsigned* __restrict__ x,
                                              unsigned* __restrict__ eout,
                                              unsigned* __restrict__ skel,
                                              int init) {
  constexpr int TOT = (NUP + 1) * (NUP + 3);   // total planes across levels
  __shared__ unsigned shm[TOT * WPP];
  int slab = blockIdx.x >> 6;                  // 256 blocks = 4 slabs x 64 z
  int z = blockIdx.x & 63;
  int tid = threadIdx.x;
  int P[NUP + 1], off[NUP + 1];
  {
    int o = 0;
    #pragma unroll
    for (int k = 0; k <= NUP; ++k) { P[k] = 2 * (NUP - k) + 3; off[k] = o; o += P[k] * WPP; }
  }
  const unsigned* xs = x + slab * WPS;
  for (int t = tid; t < P[0] * WPP; t += TPB) {
    int p = t / WPP;
    int zz = z - (NUP + 1) + p;
    shm[t] = (zz >= 0 && zz < Dn) ? xs[zz * WPP + (t % WPP)] : 0xFFFFFFFFu;
  }
  __syncthreads();
  #pragma unroll
  for (int k = 1; k <= NUP; ++k) {
    for (int t = tid; t < P[k] * WPP; t += TPB) {
      int p = t / WPP;
      int w = t - p * WPP;
      int y = w / WPR, wx = w - y * WPR;
      shm[off[k] + t] = erode_w(shm + off[k - 1], (p + 1) * WPP, w, y, wx);
    }
    __syncthreads();
  }
  for (int w = tid; w < WPP; w += TPB) {
    int y = w / WPR, wx = w - y * WPR;
    unsigned sk = 0u;
    #pragma unroll
    for (int k = 1; k <= NUP; ++k) {
      unsigned prevC = shm[off[k - 1] + ((P[k - 1] - 1) / 2) * WPP + w];
      unsigned d = dil3_w(shm + off[k], (P[k] - 1) / 2, z, w, y, wx);
      sk |= prevC & ~d;
    }
    unsigned ex = shm[off[NUP] + 1 * WPP + w];  // P[NUP]=3, center index 1
    int gi = slab * WPS + z * WPP + w;
    eout[gi] = ex;
    skel[gi] = init ? sk : (skel[gi] | sk);
  }
}

// ---- EDT pass 0 (z axis, L=64) from mask bits -> d2 floats (R5-verified) ----
__global__ __launch_bounds__(TPB) void k_edt0(const unsigned* __restrict__ Mb,
                                              float* __restrict__ out) {
  int gt = blockIdx.x * TPB + threadIdx.x;
  int c = gt % (4 * HW);
  int chunk = gt / (4 * HW);                   // 0..7
  int slab = c / HW;
  int s2d = c - slab * HW;
  int i0 = chunk * OPT;
  const unsigned* mb = Mb + slab * WPS;
  float best[OPT];
  #pragma unroll
  for (int s = 0; s < OPT; ++s) best[s] = 3.4e38f;
  float db = (float)i0;
  #pragma unroll 4
  for (int j = 0; j < Dn; ++j) {
    int bi = j * HW + s2d;
    float f = ((mb[bi >> 5] >> (bi & 31)) & 1u) ? INFD : 0.0f;
    #pragma unroll
    for (int s = 0; s < OPT; ++s) {
      float d = db + (float)s;
      best[s] = fminf(best[s], fmaf(d, d, f));
    }
    db -= 1.0f;
  }
  float* o = out + slab * S + s2d;
  #pragma unroll
  for (int s = 0; s < OPT; ++s) o[(i0 + s) * HW] = best[s];
}

// ---- fused EDT pass1(y)+pass2(x) per (slab,z) plane, + skel-masked pmax ----
// Plane staged in LDS; all values are exact f32 integers (or exactly 1e12),
// so results are bit-identical to the separate-kernel version.
__global__ __launch_bounds__(TPB) void k_edt12(float* __restrict__ D2,
                                               const unsigned* __restrict__ skel,
                                               float* __restrict__ pmax) {
  __shared__ float A[HW];                      // pass0 plane (36 KB)
  __shared__ float Bh[48 * 97];                // pass1 half-plane, padded (18.6 KB)
  __shared__ float ldsf[4];
  int slab = blockIdx.x >> 6;                  // 256 blocks
  int z = blockIdx.x & 63;
  int tid = threadIdx.x;
  int pb = slab * S + z * HW;
  for (int t = tid; t < HW / 4; t += TPB)
    ((float4*)A)[t] = ((const float4*)(D2 + pb))[t];
  __syncthreads();
  float m = 0.0f;
  #pragma unroll
  for (int h = 0; h < 2; ++h) {
    int y0 = h * 48;
    // pass1: columns x, outputs y in [y0,y0+48)
    for (int t = tid; t < 576; t += TPB) {     // 96 cols x 6 chunks
      int xx = t % 96;
      int c = t / 96;
      float best[OPT];
      #pragma unroll
      for (int s = 0; s < OPT; ++s) best[s] = 3.4e38f;
      float db = (float)(y0 + c * OPT);
      #pragma unroll 4
      for (int j = 0; j < Hn; ++j) {
        float f = A[j * 96 + xx];
        #pragma unroll
        for (int s = 0; s < OPT; ++s) {
          float d = db + (float)s;
          best[s] = fminf(best[s], fmaf(d, d, f));
        }
        db -= 1.0f;
      }
      #pragma unroll
      for (int s = 0; s < OPT; ++s) Bh[(c * OPT + s) * 97 + xx] = best[s];
    }
    __syncthreads();
    // pass2: rows y in half, outputs x; write global + masked max
    for (int t = tid; t < 576; t += TPB) {     // 48 rows x 12 chunks
      int r = t / 12;
      int chunk = t - r * 12;
      int i0 = chunk * OPT;
      float best[OPT];
      #pragma unroll
      for (int s = 0; s < OPT; ++s) best[s] = 3.4e38f;
      float db = (float)i0;
      #pragma unroll 4
      for (int j = 0; j < Wn; ++j) {
        float f = Bh[r * 97 + j];
        #pragma unroll
        for (int s = 0; s < OPT; ++s) {
          float d = db + (float)s;
          best[s] = fminf(best[s], fmaf(d, d, f));
        }
        db -= 1.0f;
      }
      int gb = pb + (y0 + r) * 96 + i0;
      float4 v0 = make_float4(best[0], best[1], best[2], best[3]);
      float4 v1 = make_float4(best[4], best[5], best[6], best[7]);
      ((float4*)(D2 + gb))[0] = v0;
      ((float4*)(D2 + gb))[1] = v1;
      unsigned wv = skel[gb >> 5] >> (gb & 31);
      #pragma unroll
      for (int s = 0; s < OPT; ++s)
        if ((wv >> s) & 1u) m = fmaxf(m, best[s]);
    }
    __syncthreads();
  }
  #pragma unroll
  for (int o = 32; o > 0; o >>= 1) m = fmaxf(m, __shfl_xor(m, o, 64));
  if ((tid & 63) == 0) ldsf[tid >> 6] = m;
  __syncthreads();
  if (tid == 0)
    pmax[blockIdx.x] = fmaxf(fmaxf(ldsf[0], ldsf[1]), fmaxf(ldsf[2], ldsf[3]));
}

// ---- sums: redundant rmax reduce + per-quad terms + last-block loss ----
__global__ __launch_bounds__(TPB) void k_sums(const float* __restrict__ d2,
                                              const unsigned* __restrict__ skel,
                                              const float* __restrict__ pmax,
                                              double* __restrict__ ps,
                                              unsigned* __restrict__ done,
                                              float* __restrict__ out) {
  __shared__ float lmax[4];
  __shared__ double ldsd[4][4];
  __shared__ unsigned isLast;
  int tid = threadIdx.x;
  // per-slab rmax: wave w reduces pmax[w*64 .. w*64+63]
  {
    float v = pmax[tid];                       // tid 0..255 == slab*64+z
    #pragma unroll
    for (int o = 32; o > 0; o >>= 1) v = fmaxf(v, __shfl_xor(v, o, 64));
    if ((tid & 63) == 0) lmax[tid >> 6] = v;
  }
  __syncthreads();
  int q = blockIdx.x * TPB + tid;              // one quad per thread
  int idx0 = q * 4;
  int b = idx0 / S;
  float rmax_p = sqrtf(lmax[b]);
  float rmax_t = sqrtf(lmax[2 + b]);
  float4 dp4 = ((const float4*)d2)[q];
  float4 dt4 = ((const float4*)(d2 + NBS))[q];
  unsigned spw = (skel[idx0 >> 5] >> (idx0 & 31)) & 0xFu;
  unsigned stw = (skel[(NBS + idx0) >> 5] >> (idx0 & 31)) & 0xFu;
  const float* dp = &dp4.x;
  const float* dt = &dt4.x;
  double acc[4] = {0.0, 0.0, 0.0, 0.0};
  #pragma unroll
  for (int s = 0; s < 4; ++s) {
    float dist_p = sqrtf(dp[s]);
    float dist_t = sqrtf(dt[s]);
    bool sp = (spw >> s) & 1u;
    bool st = (stw >> s) & 1u;
    float q_vp = (rmax_p > 0.0f) ? dist_p / rmax_p : dist_p;
    float q_vl = (rmax_t > 0.0f) ? dist_t / rmax_t : dist_t;
    float q_spvp = sp ? q_vp : 0.0f;
    float q_slvl = st ? q_vl : 0.0f;
    float q_sp = sp ? (1.0f + EPSf) / (q_spvp * q_spvp + EPSf) : 0.0f;
    float q_sl = st ? (1.0f + EPSf) / (q_slvl * q_slvl + EPSf) : 0.0f;
    acc[0] += (double)(q_sp * q_vl);
    acc[1] += (double)(((q_spvp != 0.0f) && (q_slvl == 0.0f)) ? q_spvp * q_sp
                                                              : q_slvl * q_sp);
    acc[2] += (double)(q_sl * q_vp);
    acc[3] += (double)(((q_slvl != 0.0f) && (q_spvp == 0.0f)) ? q_slvl * q_sl
                                                              : q_spvp * q_sl);
  }
  #pragma unroll
  for (int k = 0; k < 4; ++k)
    #pragma unroll
    for (int o = 32; o > 0; o >>= 1)
      acc[k] += __shfl_xor(acc[k], o, 64);
  if ((tid & 63) == 0) {
    #pragma unroll
    for (int k = 0; k < 4; ++k) ldsd[tid >> 6][k] = acc[k];
  }
  __syncthreads();
  if (tid == 0) {
    #pragma unroll
    for (int k = 0; k < 4; ++k)
      ps[blockIdx.x * 4 + k] = ldsd[0][k] + ldsd[1][k] + ldsd[2][k] + ldsd[3][k];
    __threadfence();
    unsigned ticket = __hip_atomic_fetch_add(done, 1u, __ATOMIC_ACQ_REL,
                                             __HIP_MEMORY_SCOPE_AGENT);
    isLast = (ticket == (unsigned)(BLK_SUMS - 1)) ? 1u : 0u;
  }
  __syncthreads();
  if (isLast) {
    __threadfence();                           // acquire other blocks' ps writes
    double s[4] = {0.0, 0.0, 0.0, 0.0};
    for (int i = tid; i < BLK_SUMS; i += TPB) {
      s[0] += ps[i * 4 + 0];
      s[1] += ps[i * 4 + 1];
      s[2] += ps[i * 4 + 2];
      s[3] += ps[i * 4 + 3];
    }
    #pragma unroll
    for (int k = 0; k < 4; ++k)
      #pragma unroll
      for (int o = 32; o > 0; o >>= 1)
        s[k] += __shfl_xor(s[k], o, 64);
    if ((tid & 63) == 0) {
      #pragma unroll
      for (int k = 0; k < 4; ++k) ldsd[tid >> 6][k] = s[k];
    }
    __syncthreads();
    if (tid == 0) {
      double tot[4];
      #pragma unroll
      for (int k = 0; k < 4; ++k)
        tot[k] = ldsd[0][k] + ldsd[1][k] + ldsd[2][k] + ldsd[3][k];
      double wp = (tot[0] + 1.0) / (tot[1] + 1.0);
      double ws = (tot[2] + 1.0) / (tot[3] + 1.0);
      out[0] = (float)(1.0 - 2.0 * (wp * ws) / (wp + ws));
    }
  }
}

} // namespace

extern "C" void kernel_launch(void* const* d_in, const int* in_sizes, int n_in,
                              void* d_out, int out_size, void* d_ws, size_t ws_size,
                              hipStream_t stream) {
  (void)in_sizes; (void)n_in; (void)out_size; (void)ws_size;
  const float* logits = (const float*)d_in[0];   // [B,2,D,H,W] f32
  const int* labels   = (const int*)d_in[1];     // [B,1,D,H,W] i32
  float* out = (float*)d_out;

  float* D2 = (float*)d_ws;                  // EDT d2 (in-place through edt12)
  unsigned* MB    = (unsigned*)(D2 + NT);    // pristine masks
  unsigned* XB    = MB + NTW;
  unsigned* EB    = XB + NTW;
  unsigned* SKELB = EB + NTW;
  float* PMAX  = (float*)(SKELB + NTW);      // 256 per-plane d2 maxes
  double* PS   = (double*)(PMAX + 256);      // 1152x4 doubles (8B-aligned)
  unsigned* DONE = (unsigned*)(PS + 4 * BLK_SUMS);

  dim3 blk(TPB);

  k_binarize<<<BLK_NBS, blk, 0, stream>>>(logits, labels, MB, DONE);

  // skeleton: 11 updates = 4 + 4 + 3 (3 launches, 256 blocks each)
  k_skel<4><<<256, blk, 0, stream>>>(MB, XB, SKELB, 1);
  k_skel<4><<<256, blk, 0, stream>>>(XB, EB, SKELB, 0);
  k_skel<3><<<256, blk, 0, stream>>>(EB, XB, SKELB, 0);

  // exact EDT: pass0, then fused pass1+pass2 (+pmax)
  k_edt0<<<BLK_EDT0, blk, 0, stream>>>(MB, D2);
  k_edt12<<<256, blk, 0, stream>>>(D2, SKELB, PMAX);

  // weighted sums + rmax + loss (last-block reduction)
  k_sums<<<BLK_SUMS, blk, 0, stream>>>(D2, SKELB, PMAX, PS, DONE, out);
}

// Round 9
// 171.443 us; speedup vs baseline: 7.2979x; 1.3183x over previous
//
#include <hip/hip_runtime.h>

namespace {

constexpr int Bn = 2;
constexpr int Dn = 64;
constexpr int Hn = 96;
constexpr int Wn = 96;
constexpr int HW = Hn * Wn;          // 9216
constexpr int S  = Dn * HW;          // 589824 per (vol,batch) slab
constexpr int NBS = Bn * S;          // 1179648
constexpr int NT  = 2 * NBS;         // 2359296 (slabs: predB0,predB1,truthB0,truthB1)
constexpr int WPR = Wn / 32;         // 3 words per x-row
constexpr int WPP = HW / 32;         // 288 words per z-plane
constexpr int WPS = S / 32;          // 18432 words per slab
constexpr int NTW = NT / 32;         // 73728 packed words
constexpr float INFD = 1e12f;
constexpr float EPSf = 1e-7f;
constexpr int TPB = 256;
constexpr int BLK_NBS = NBS / TPB;   // 4608
constexpr int OPT = 8;               // EDT outputs per thread
constexpr int BLK_EDT0 = NT / OPT / TPB;  // 1152
constexpr int BLK_SUMS = NBS / 4 / TPB;   // 1152 (one quad per thread)

constexpr int skel_tot(int nup) {
  int t = 0;
  for (int k = 0; k <= nup; ++k)
    t += (2 * (nup - k) + 3) * (24 + 2 * (nup + 1 - k)) * 3;
  return t;
}

// ---- binarize both masks (bit-packed via ballot); zero the DONE ticket ----
__global__ __launch_bounds__(TPB) void k_binarize(const float* __restrict__ logits,
                                                  const int* __restrict__ labels,
                                                  unsigned* __restrict__ Mb,
                                                  unsigned* __restrict__ done) {
  if (blockIdx.x == 0 && threadIdx.x == 0) done[0] = 0u;
  int idx = blockIdx.x * TPB + threadIdx.x;     // over NBS
  int b = idx / S;
  int s = idx - b * S;
  float l0 = logits[(b * 2 + 0) * S + s];
  float l1 = logits[(b * 2 + 1) * S + s];
  bool vp = l1 > l0;                            // softmax(p1)>0.5 <=> l1>l0
  bool vt = labels[idx] > 0;
  unsigned long long mp = __ballot(vp);
  unsigned long long mt = __ballot(vt);
  int lane = threadIdx.x & 63;
  if (lane == 0) {
    Mb[idx >> 5]         = (unsigned)mp;
    Mb[(NBS + idx) >> 5] = (unsigned)mt;
  } else if (lane == 32) {
    Mb[idx >> 5]         = (unsigned)(mp >> 32);
    Mb[(NBS + idx) >> 5] = (unsigned)(mt >> 32);
  }
}

// ---- NUP chained skeleton updates, quarter-plane (24 y-rows) per block ----
// Level 0 = X (loaded; volume-OOB halo = 1s); level k = erode(level k-1).
// skel (|)= OR_k [ center(L_{k-1}) & ~dil3(L_k) ];  eout = center(L_NUP).
// Halo-superset correctness: y-tiling verified in R6, NUP-chain in R8 (absmax 0).
template <int NUP>
__global__ __launch_bounds__(TPB) void k_skel(const unsigned* __restrict__ x,
                                              unsigned* __restrict__ eout,
                                              unsigned* __restrict__ skel,
                                              int init) {
  constexpr int TOTW = skel_tot(NUP);
  constexpr int P0 = 2 * NUP + 3;
  constexpr int R0 = 24 + 2 * (NUP + 1);
  __shared__ unsigned shm[TOTW];
  __shared__ unsigned skbuf[72];
  int slab = blockIdx.x >> 8;                  // 1024 blocks = slab(4) x z(64) x q(4)
  int z = (blockIdx.x >> 2) & 63;
  int y0 = (blockIdx.x & 3) * 24;
  int tid = threadIdx.x;
  const unsigned* xs = x + slab * WPS;
  for (int t = tid; t < P0 * R0 * 3; t += TPB) {
    int p = t / (R0 * 3); int rem = t - p * (R0 * 3); int r = rem / 3; int wx = rem - r * 3;
    int zz = z - (NUP + 1) + p, yy = y0 - (NUP + 1) + r;
    shm[t] = (zz >= 0 && zz < Dn && yy >= 0 && yy < Hn)
               ? xs[zz * WPP + yy * WPR + wx] : 0xFFFFFFFFu;
  }
  for (int t = tid; t < 72; t += TPB) skbuf[t] = 0u;
  __syncthreads();
  int offPrev = 0;
  int offCur = P0 * R0 * 3;
  #pragma unroll
  for (int k = 1; k <= NUP; ++k) {
    const int Pk = 2 * (NUP - k) + 3, Rk = 24 + 2 * (NUP + 1 - k);
    const int Rp = Rk + 2;                     // R[k-1]
    const int ps = Rp * 3;
    for (int t = tid; t < Pk * Rk * 3; t += TPB) {
      int p = t / (Rk * 3); int rem = t - p * (Rk * 3); int r = rem / 3; int wx = rem - r * 3;
      const unsigned* A = shm + offPrev;
      int ci = ((p + 1) * Rp + (r + 1)) * 3 + wx;
      unsigned v = A[ci];
      unsigned l = (v << 1) | (wx > 0 ? (A[ci - 1] >> 31) : 1u);
      unsigned rr = (v >> 1) | (wx < 2 ? (A[ci + 1] << 31) : 0x80000000u);
      shm[offCur + t] = v & l & rr & A[ci - 3] & A[ci + 3] & A[ci - ps] & A[ci + ps];
    }
    offPrev = offCur;
    offCur += Pk * Rk * 3;
    __syncthreads();
  }
  // sk contributions: 72 words x NUP levels spread across threads
  for (int t = tid; t < 72 * NUP; t += TPB) {
    int word = t % 72;
    int k = t / 72 + 1;
    int ro = word / 3, wx = word - ro * 3;
    int yy = y0 + ro;
    int offk = 0;
    for (int j = 0; j < k; ++j)
      offk += (2 * (NUP - j) + 3) * (24 + 2 * (NUP + 1 - j)) * 3;
    int Pk = 2 * (NUP - k) + 3, Rk = 24 + 2 * (NUP + 1 - k);
    int Pp = Pk + 2, Rp = Rk + 2;
    int offkm1 = offk - Pp * Rp * 3;
    const unsigned* A = shm + offk;
    int pc = (Pk - 1) / 2;
    int rb = ro + (NUP + 1 - k);
    unsigned acc = 0u;
    #pragma unroll
    for (int dz = -1; dz <= 1; ++dz) {
      if (z + dz < 0 || z + dz >= Dn) continue;
      #pragma unroll
      for (int dy = -1; dy <= 1; ++dy) {
        if (yy + dy < 0 || yy + dy >= Hn) continue;
        int ii = ((pc + dz) * Rk + (rb + dy)) * 3 + wx;
        unsigned c = A[ii];
        unsigned pw = (wx > 0) ? A[ii - 1] : 0u;
        unsigned nw = (wx < 2) ? A[ii + 1] : 0u;
        acc |= c | ((c << 1) | (pw >> 31)) | ((c >> 1) | (nw << 31));
      }
    }
    const unsigned* Ap = shm + offkm1;
    unsigned prevC = Ap[(((Pp - 1) / 2) * Rp + (ro + (NUP + 2 - k))) * 3 + wx];
    unsigned contrib = prevC & ~acc;
    if (contrib) atomicOr(&skbuf[word], contrib);
  }
  __syncthreads();
  for (int t = tid; t < 72; t += TPB) {
    int ro = t / 3, wx = t - ro * 3;
    unsigned ex = shm[TOTW - 234 + (26 + ro + 1) * 3 + wx];  // level NUP, plane 1, row ro+1
    int gi = slab * WPS + z * WPP + (y0 + ro) * WPR + wx;
    eout[gi] = ex;
    unsigned sk = skbuf[t];
    skel[gi] = init ? sk : (skel[gi] | sk);
  }
}

// ---- EDT pass 0 (z axis, L=64) from mask bits -> d2 floats (R5-verified) ----
__global__ __launch_bounds__(TPB) void k_edt0(const unsigned* __restrict__ Mb,
                                              float* __restrict__ out) {
  int gt = blockIdx.x * TPB + threadIdx.x;
  int c = gt % (4 * HW);
  int chunk = gt / (4 * HW);                   // 0..7
  int slab = c / HW;
  int s2d = c - slab * HW;
  int i0 = chunk * OPT;
  const unsigned* mb = Mb + slab * WPS;
  float best[OPT];
  #pragma unroll
  for (int s = 0; s < OPT; ++s) best[s] = 3.4e38f;
  float db = (float)i0;
  #pragma unroll 4
  for (int j = 0; j < Dn; ++j) {
    int bi = j * HW + s2d;
    float f = ((mb[bi >> 5] >> (bi & 31)) & 1u) ? INFD : 0.0f;
    #pragma unroll
    for (int s = 0; s < OPT; ++s) {
      float d = db + (float)s;
      best[s] = fminf(best[s], fmaf(d, d, f));
    }
    db -= 1.0f;
  }
  float* o = out + slab * S + s2d;
  #pragma unroll
  for (int s = 0; s < OPT; ++s) o[(i0 + s) * HW] = best[s];
}

// ---- fused EDT pass1(y)+pass2(x), quarter-plane per block (1024 blocks) ----
// Pass1 reads D2 (edt0 output) from global; pass2 writes EF (separate buffer,
// avoiding the in-place cross-block race). Bit-exact: same fmaf/fminf chain.
__global__ __launch_bounds__(TPB) void k_edt12(const float* __restrict__ D2,
                                               float* __restrict__ EF,
                                               const unsigned* __restrict__ skel,
                                               float* __restrict__ pmax) {
  __shared__ float Bh[24 * 97];                // pass1 quarter, padded (9.3 KB)
  __shared__ float ldsf[4];
  int slab = blockIdx.x >> 8;                  // 1024 blocks = slab(4) x z(64) x q(4)
  int z = (blockIdx.x >> 2) & 63;
  int y0 = (blockIdx.x & 3) * 24;
  int tid = threadIdx.x;
  int pb = slab * S + z * HW;
  // pass1: full y min-conv per column, outputs y in [y0, y0+24)
  for (int t = tid; t < 288; t += TPB) {       // 96 cols x 3 chunks
    int xx = t % 96;
    int c = t / 96;
    float best[OPT];
    #pragma unroll
    for (int s = 0; s < OPT; ++s) best[s] = 3.4e38f;
    float db = (float)(y0 + c * OPT);
    #pragma unroll 4
    for (int j = 0; j < Hn; ++j) {
      float f = D2[pb + j * 96 + xx];
      #pragma unroll
      for (int s = 0; s < OPT; ++s) {
        float d = db + (float)s;
        best[s] = fminf(best[s], fmaf(d, d, f));
      }
      db -= 1.0f;
    }
    #pragma unroll
    for (int s = 0; s < OPT; ++s) Bh[(c * OPT + s) * 97 + xx] = best[s];
  }
  __syncthreads();
  // pass2: x min-conv per row, write EF + masked max
  float m = 0.0f;
  for (int t = tid; t < 288; t += TPB) {       // 24 rows x 12 chunks
    int r = t / 12;
    int chunk = t - r * 12;
    int i0 = chunk * OPT;
    float best[OPT];
    #pragma unroll
    for (int s = 0; s < OPT; ++s) best[s] = 3.4e38f;
    float db = (float)i0;
    #pragma unroll 4
    for (int j = 0; j < Wn; ++j) {
      float f = Bh[r * 97 + j];
      #pragma unroll
      for (int s = 0; s < OPT; ++s) {
        float d = db + (float)s;
        best[s] = fminf(best[s], fmaf(d, d, f));
      }
      db -= 1.0f;
    }
    int gb = pb + (y0 + r) * 96 + i0;
    ((float4*)(EF + gb))[0] = make_float4(best[0], best[1], best[2], best[3]);
    ((float4*)(EF + gb))[1] = make_float4(best[4], best[5], best[6], best[7]);
    unsigned wv = skel[gb >> 5] >> (gb & 31);
    #pragma unroll
    for (int s = 0; s < OPT; ++s)
      if ((wv >> s) & 1u) m = fmaxf(m, best[s]);
  }
  #pragma unroll
  for (int o = 32; o > 0; o >>= 1) m = fmaxf(m, __shfl_xor(m, o, 64));
  if ((tid & 63) == 0) ldsf[tid >> 6] = m;
  __syncthreads();
  if (tid == 0)
    pmax[blockIdx.x] = fmaxf(fmaxf(ldsf[0], ldsf[1]), fmaxf(ldsf[2], ldsf[3]));
}

// ---- sums: redundant rmax reduce + per-quad terms + last-block loss ----
__global__ __launch_bounds__(TPB) void k_sums(const float* __restrict__ d2,
                                              const unsigned* __restrict__ skel,
                                              const float* __restrict__ pmax,
                                              double* __restrict__ ps,
                                              unsigned* __restrict__ done,
                                              float* __restrict__ out) {
  __shared__ float lmax[4];
  __shared__ double ldsd[4][4];
  __shared__ unsigned isLast;
  int tid = threadIdx.x;
  // per-slab rmax: wave w reduces pmax[w*256 .. w*256+255]
  {
    int wave = tid >> 6, lane = tid & 63;
    const float* pw = pmax + wave * 256;
    float v = fmaxf(fmaxf(pw[lane], pw[lane + 64]),
                    fmaxf(pw[lane + 128], pw[lane + 192]));
    #pragma unroll
    for (int o = 32; o > 0; o >>= 1) v = fmaxf(v, __shfl_xor(v, o, 64));
    if (lane == 0) lmax[wave] = v;
  }
  __syncthreads();
  int q = blockIdx.x * TPB + tid;              // one quad per thread
  int idx0 = q * 4;
  int b = idx0 / S;
  float rmax_p = sqrtf(lmax[b]);
  float rmax_t = sqrtf(lmax[2 + b]);
  float4 dp4 = ((const float4*)d2)[q];
  float4 dt4 = ((const float4*)(d2 + NBS))[q];
  unsigned spw = (skel[idx0 >> 5] >> (idx0 & 31)) & 0xFu;
  unsigned stw = (skel[(NBS + idx0) >> 5] >> (idx0 & 31)) & 0xFu;
  const float* dp = &dp4.x;
  const float* dt = &dt4.x;
  double acc[4] = {0.0, 0.0, 0.0, 0.0};
  #pragma unroll
  for (int s = 0; s < 4; ++s) {
    float dist_p = sqrtf(dp[s]);
    float dist_t = sqrtf(dt[s]);
    bool sp = (spw >> s) & 1u;
    bool st = (stw >> s) & 1u;
    float q_vp = (rmax_p > 0.0f) ? dist_p / rmax_p : dist_p;
    float q_vl = (rmax_t > 0.0f) ? dist_t / rmax_t : dist_t;
    float q_spvp = sp ? q_vp : 0.0f;
    float q_slvl = st ? q_vl : 0.0f;
    float q_sp = sp ? (1.0f + EPSf) / (q_spvp * q_spvp + EPSf) : 0.0f;
    float q_sl = st ? (1.0f + EPSf) / (q_slvl * q_slvl + EPSf) : 0.0f;
    acc[0] += (double)(q_sp * q_vl);
    acc[1] += (double)(((q_spvp != 0.0f) && (q_slvl == 0.0f)) ? q_spvp * q_sp
                                                              : q_slvl * q_sp);
    acc[2] += (double)(q_sl * q_vp);
    acc[3] += (double)(((q_slvl != 0.0f) && (q_spvp == 0.0f)) ? q_slvl * q_sl
                                                              : q_spvp * q_sl);
  }
  #pragma unroll
  for (int k = 0; k < 4; ++k)
    #pragma unroll
    for (int o = 32; o > 0; o >>= 1)
      acc[k] += __shfl_xor(acc[k], o, 64);
  if ((tid & 63) == 0) {
    #pragma unroll
    for (int k = 0; k < 4; ++k) ldsd[tid >> 6][k] = acc[k];
  }
  __syncthreads();
  if (tid == 0) {
    #pragma unroll
    for (int k = 0; k < 4; ++k)
      ps[blockIdx.x * 4 + k] = ldsd[0][k] + ldsd[1][k] + ldsd[2][k] + ldsd[3][k];
    __threadfence();
    unsigned ticket = __hip_atomic_fetch_add(done, 1u, __ATOMIC_ACQ_REL,
                                             __HIP_MEMORY_SCOPE_AGENT);
    isLast = (ticket == (unsigned)(BLK_SUMS - 1)) ? 1u : 0u;
  }
  __syncthreads();
  if (isLast) {
    __threadfence();                           // acquire other blocks' ps writes
    double s[4] = {0.0, 0.0, 0.0, 0.0};
    for (int i = tid; i < BLK_SUMS; i += TPB) {
      s[0] += ps[i * 4 + 0];
      s[1] += ps[i * 4 + 1];
      s[2] += ps[i * 4 + 2];
      s[3] += ps[i * 4 + 3];
    }
    #pragma unroll
    for (int k = 0; k < 4; ++k)
      #pragma unroll
      for (int o = 32; o > 0; o >>= 1)
        s[k] += __shfl_xor(s[k], o, 64);
    if ((tid & 63) == 0) {
      #pragma unroll
      for (int k = 0; k < 4; ++k) ldsd[tid >> 6][k] = s[k];
    }
    __syncthreads();
    if (tid == 0) {
      double tot[4];
      #pragma unroll
      for (int k = 0; k < 4; ++k)
        tot[k] = ldsd[0][k] + ldsd[1][k] + ldsd[2][k] + ldsd[3][k];
      double wp = (tot[0] + 1.0) / (tot[1] + 1.0);
      double ws = (tot[2] + 1.0) / (tot[3] + 1.0);
      out[0] = (float)(1.0 - 2.0 * (wp * ws) / (wp + ws));
    }
  }
}

} // namespace

extern "C" void kernel_launch(void* const* d_in, const int* in_sizes, int n_in,
                              void* d_out, int out_size, void* d_ws, size_t ws_size,
                              hipStream_t stream) {
  (void)in_sizes; (void)n_in; (void)out_size; (void)ws_size;
  const float* logits = (const float*)d_in[0];   // [B,2,D,H,W] f32
  const int* labels   = (const int*)d_in[1];     // [B,1,D,H,W] i32
  float* out = (float*)d_out;

  float* D2 = (float*)d_ws;                  // edt0 output
  float* EF = D2 + NT;                       // edt12 output (final d2)
  unsigned* MB    = (unsigned*)(EF + NT);    // pristine masks
  unsigned* XB    = MB + NTW;
  unsigned* EB    = XB + NTW;
  unsigned* SKELB = EB + NTW;
  float* PMAX  = (float*)(SKELB + NTW);      // 1024 per-quarter-plane d2 maxes
  double* PS   = (double*)(PMAX + 1024);     // 1152x4 doubles (8B-aligned)
  unsigned* DONE = (unsigned*)(PS + 4 * BLK_SUMS);

  dim3 blk(TPB);

  k_binarize<<<BLK_NBS, blk, 0, stream>>>(logits, labels, MB, DONE);

  // skeleton: 11 updates = 4 + 4 + 3 (3 launches, 1024 blocks each)
  k_skel<4><<<1024, blk, 0, stream>>>(MB, XB, SKELB, 1);
  k_skel<4><<<1024, blk, 0, stream>>>(XB, EB, SKELB, 0);
  k_skel<3><<<1024, blk, 0, stream>>>(EB, XB, SKELB, 0);

  // exact EDT: pass0, then fused pass1+pass2 (+pmax), 1024 blocks
  k_edt0<<<BLK_EDT0, blk, 0, stream>>>(MB, D2);
  k_edt12<<<1024, blk, 0, stream>>>(D2, EF, SKELB, PMAX);

  // weighted sums + rmax + loss (last-block reduction)
  k_sums<<<BLK_SUMS, blk, 0, stream>>>(EF, SKELB, PMAX, PS, DONE, out);
}

// Round 10
// 141.184 us; speedup vs baseline: 8.8620x; 1.2143x over previous
//
#include <hip/hip_runtime.h>

namespace {

constexpr int Bn = 2;
constexpr int Dn = 64;
constexpr int Hn = 96;
constexpr int Wn = 96;
constexpr int HW = Hn * Wn;          // 9216
constexpr int S  = Dn * HW;          // 589824 per (vol,batch) slab
constexpr int NBS = Bn * S;          // 1179648
constexpr int NT  = 2 * NBS;         // 2359296 (slabs: predB0,predB1,truthB0,truthB1)
constexpr int WPR = Wn / 32;         // 3 words per x-row
constexpr int WPP = HW / 32;         // 288 words per z-plane
constexpr int WPS = S / 32;          // 18432 words per slab
constexpr int NTW = NT / 32;         // 73728 packed words
constexpr float INFD = 1e12f;
constexpr float EPSf = 1e-7f;
constexpr int TPB = 256;
constexpr int BLK_NBS = NBS / TPB;   // 4608
constexpr int OPT = 8;               // EDT outputs per thread
constexpr int BLK_EDT0 = NT / OPT / TPB;  // 1152
constexpr int BLK_SUMS = NBS / 4 / TPB;   // 1152 (one quad per thread)

constexpr int skel_tot(int nup) {
  int t = 0;
  for (int k = 0; k <= nup; ++k)
    t += (2 * (nup - k) + 3) * (24 + 2 * (nup + 1 - k)) * 3;
  return t;
}

// ---- binarize both masks (bit-packed via ballot) ----
__global__ __launch_bounds__(TPB) void k_binarize(const float* __restrict__ logits,
                                                  const int* __restrict__ labels,
                                                  unsigned* __restrict__ Mb) {
  int idx = blockIdx.x * TPB + threadIdx.x;     // over NBS
  int b = idx / S;
  int s = idx - b * S;
  float l0 = logits[(b * 2 + 0) * S + s];
  float l1 = logits[(b * 2 + 1) * S + s];
  bool vp = l1 > l0;                            // softmax(p1)>0.5 <=> l1>l0
  bool vt = labels[idx] > 0;
  unsigned long long mp = __ballot(vp);
  unsigned long long mt = __ballot(vt);
  int lane = threadIdx.x & 63;
  if (lane == 0) {
    Mb[idx >> 5]         = (unsigned)mp;
    Mb[(NBS + idx) >> 5] = (unsigned)mt;
  } else if (lane == 32) {
    Mb[idx >> 5]         = (unsigned)(mp >> 32);
    Mb[(NBS + idx) >> 5] = (unsigned)(mt >> 32);
  }
}

// ---- NUP chained skeleton updates, quarter-plane (24 y-rows) per block ----
// Level 0 = X (loaded; volume-OOB halo = 1s); level k = erode(level k-1).
// skel (|)= OR_k [ center(L_{k-1}) & ~dil3(L_k) ];  eout = center(L_NUP).
// Halo-superset correctness: y-tiling verified in R6, NUP-chain in R8 (absmax 0).
template <int NUP>
__global__ __launch_bounds__(TPB) void k_skel(const unsigned* __restrict__ x,
                                              unsigned* __restrict__ eout,
                                              unsigned* __restrict__ skel,
                                              int init) {
  constexpr int TOTW = skel_tot(NUP);
  constexpr int P0 = 2 * NUP + 3;
  constexpr int R0 = 24 + 2 * (NUP + 1);
  __shared__ unsigned shm[TOTW];
  __shared__ unsigned skbuf[72];
  int slab = blockIdx.x >> 8;                  // 1024 blocks = slab(4) x z(64) x q(4)
  int z = (blockIdx.x >> 2) & 63;
  int y0 = (blockIdx.x & 3) * 24;
  int tid = threadIdx.x;
  const unsigned* xs = x + slab * WPS;
  for (int t = tid; t < P0 * R0 * 3; t += TPB) {
    int p = t / (R0 * 3); int rem = t - p * (R0 * 3); int r = rem / 3; int wx = rem - r * 3;
    int zz = z - (NUP + 1) + p, yy = y0 - (NUP + 1) + r;
    shm[t] = (zz >= 0 && zz < Dn && yy >= 0 && yy < Hn)
               ? xs[zz * WPP + yy * WPR + wx] : 0xFFFFFFFFu;
  }
  for (int t = tid; t < 72; t += TPB) skbuf[t] = 0u;
  __syncthreads();
  int offPrev = 0;
  int offCur = P0 * R0 * 3;
  #pragma unroll
  for (int k = 1; k <= NUP; ++k) {
    const int Pk = 2 * (NUP - k) + 3, Rk = 24 + 2 * (NUP + 1 - k);
    const int Rp = Rk + 2;                     // R[k-1]
    const int ps = Rp * 3;
    for (int t = tid; t < Pk * Rk * 3; t += TPB) {
      int p = t / (Rk * 3); int rem = t - p * (Rk * 3); int r = rem / 3; int wx = rem - r * 3;
      const unsigned* A = shm + offPrev;
      int ci = ((p + 1) * Rp + (r + 1)) * 3 + wx;
      unsigned v = A[ci];
      unsigned l = (v << 1) | (wx > 0 ? (A[ci - 1] >> 31) : 1u);
      unsigned rr = (v >> 1) | (wx < 2 ? (A[ci + 1] << 31) : 0x80000000u);
      shm[offCur + t] = v & l & rr & A[ci - 3] & A[ci + 3] & A[ci - ps] & A[ci + ps];
    }
    offPrev = offCur;
    offCur += Pk * Rk * 3;
    __syncthreads();
  }
  // sk contributions: 72 words x NUP levels spread across threads
  for (int t = tid; t < 72 * NUP; t += TPB) {
    int word = t % 72;
    int k = t / 72 + 1;
    int ro = word / 3, wx = word - ro * 3;
    int yy = y0 + ro;
    int offk = 0;
    for (int j = 0; j < k; ++j)
      offk += (2 * (NUP - j) + 3) * (24 + 2 * (NUP + 1 - j)) * 3;
    int Pk = 2 * (NUP - k) + 3, Rk = 24 + 2 * (NUP + 1 - k);
    int Pp = Pk + 2, Rp = Rk + 2;
    int offkm1 = offk - Pp * Rp * 3;
    const unsigned* A = shm + offk;
    int pc = (Pk - 1) / 2;
    int rb = ro + (NUP + 1 - k);
    unsigned acc = 0u;
    #pragma unroll
    for (int dz = -1; dz <= 1; ++dz) {
      if (z + dz < 0 || z + dz >= Dn) continue;
      #pragma unroll
      for (int dy = -1; dy <= 1; ++dy) {
        if (yy + dy < 0 || yy + dy >= Hn) continue;
        int ii = ((pc + dz) * Rk + (rb + dy)) * 3 + wx;
        unsigned c = A[ii];
        unsigned pw = (wx > 0) ? A[ii - 1] : 0u;
        unsigned nw = (wx < 2) ? A[ii + 1] : 0u;
        acc |= c | ((c << 1) | (pw >> 31)) | ((c >> 1) | (nw << 31));
      }
    }
    const unsigned* Ap = shm + offkm1;
    unsigned prevC = Ap[(((Pp - 1) / 2) * Rp + (ro + (NUP + 2 - k))) * 3 + wx];
    unsigned contrib = prevC & ~acc;
    if (contrib) atomicOr(&skbuf[word], contrib);
  }
  __syncthreads();
  for (int t = tid; t < 72; t += TPB) {
    int ro = t / 3, wx = t - ro * 3;
    unsigned ex = shm[TOTW - 234 + (26 + ro + 1) * 3 + wx];  // level NUP, plane 1, row ro+1
    int gi = slab * WPS + z * WPP + (y0 + ro) * WPR + wx;
    eout[gi] = ex;
    unsigned sk = skbuf[t];
    skel[gi] = init ? sk : (skel[gi] | sk);
  }
}

// ---- EDT pass 0 (z axis, L=64) from mask bits -> d2 floats (R5-verified) ----
__global__ __launch_bounds__(TPB) void k_edt0(const unsigned* __restrict__ Mb,
                                              float* __restrict__ out) {
  int gt = blockIdx.x * TPB + threadIdx.x;
  int c = gt % (4 * HW);
  int chunk = gt / (4 * HW);                   // 0..7
  int slab = c / HW;
  int s2d = c - slab * HW;
  int i0 = chunk * OPT;
  const unsigned* mb = Mb + slab * WPS;
  float best[OPT];
  #pragma unroll
  for (int s = 0; s < OPT; ++s) best[s] = 3.4e38f;
  float db = (float)i0;
  #pragma unroll 4
  for (int j = 0; j < Dn; ++j) {
    int bi = j * HW + s2d;
    float f = ((mb[bi >> 5] >> (bi & 31)) & 1u) ? INFD : 0.0f;
    #pragma unroll
    for (int s = 0; s < OPT; ++s) {
      float d = db + (float)s;
      best[s] = fminf(best[s], fmaf(d, d, f));
    }
    db -= 1.0f;
  }
  float* o = out + slab * S + s2d;
  #pragma unroll
  for (int s = 0; s < OPT; ++s) o[(i0 + s) * HW] = best[s];
}

// ---- fused EDT pass1(y)+pass2(x), quarter-plane per block (1024 blocks) ----
__global__ __launch_bounds__(TPB) void k_edt12(const float* __restrict__ D2,
                                               float* __restrict__ EF,
                                               const unsigned* __restrict__ skel,
                                               float* __restrict__ pmax) {
  __shared__ float Bh[24 * 97];                // pass1 quarter, padded (9.3 KB)
  __shared__ float ldsf[4];
  int slab = blockIdx.x >> 8;                  // 1024 blocks = slab(4) x z(64) x q(4)
  int z = (blockIdx.x >> 2) & 63;
  int y0 = (blockIdx.x & 3) * 24;
  int tid = threadIdx.x;
  int pb = slab * S + z * HW;
  // pass1: full y min-conv per column, outputs y in [y0, y0+24)
  for (int t = tid; t < 288; t += TPB) {       // 96 cols x 3 chunks
    int xx = t % 96;
    int c = t / 96;
    float best[OPT];
    #pragma unroll
    for (int s = 0; s < OPT; ++s) best[s] = 3.4e38f;
    float db = (float)(y0 + c * OPT);
    #pragma unroll 4
    for (int j = 0; j < Hn; ++j) {
      float f = D2[pb + j * 96 + xx];
      #pragma unroll
      for (int s = 0; s < OPT; ++s) {
        float d = db + (float)s;
        best[s] = fminf(best[s], fmaf(d, d, f));
      }
      db -= 1.0f;
    }
    #pragma unroll
    for (int s = 0; s < OPT; ++s) Bh[(c * OPT + s) * 97 + xx] = best[s];
  }
  __syncthreads();
  // pass2: x min-conv per row, write EF + masked max
  float m = 0.0f;
  for (int t = tid; t < 288; t += TPB) {       // 24 rows x 12 chunks
    int r = t / 12;
    int chunk = t - r * 12;
    int i0 = chunk * OPT;
    float best[OPT];
    #pragma unroll
    for (int s = 0; s < OPT; ++s) best[s] = 3.4e38f;
    float db = (float)i0;
    #pragma unroll 4
    for (int j = 0; j < Wn; ++j) {
      float f = Bh[r * 97 + j];
      #pragma unroll
      for (int s = 0; s < OPT; ++s) {
        float d = db + (float)s;
        best[s] = fminf(best[s], fmaf(d, d, f));
      }
      db -= 1.0f;
    }
    int gb = pb + (y0 + r) * 96 + i0;
    ((float4*)(EF + gb))[0] = make_float4(best[0], best[1], best[2], best[3]);
    ((float4*)(EF + gb))[1] = make_float4(best[4], best[5], best[6], best[7]);
    unsigned wv = skel[gb >> 5] >> (gb & 31);
    #pragma unroll
    for (int s = 0; s < OPT; ++s)
      if ((wv >> s) & 1u) m = fmaxf(m, best[s]);
  }
  #pragma unroll
  for (int o = 32; o > 0; o >>= 1) m = fmaxf(m, __shfl_xor(m, o, 64));
  if ((tid & 63) == 0) ldsf[tid >> 6] = m;
  __syncthreads();
  if (tid == 0)
    pmax[blockIdx.x] = fmaxf(fmaxf(ldsf[0], ldsf[1]), fmaxf(ldsf[2], ldsf[3]));
}

// ---- sums: redundant rmax reduce + per-quad terms -> plain partial stores ----
// (R9 post-mortem: per-block threadfence+ACQ_REL ticket forced an L2
//  writeback/invalidate per block -> 44 us. Plain stores + separate final
//  kernel lets the kernel-boundary do ONE release for everyone.)
__global__ __launch_bounds__(TPB) void k_sums(const float* __restrict__ d2,
                                              const unsigned* __restrict__ skel,
                                              const float* __restrict__ pmax,
                                              double* __restrict__ ps) {
  __shared__ float lmax[4];
  __shared__ double ldsd[4][4];
  int tid = threadIdx.x;
  // per-slab rmax: wave w reduces pmax[w*256 .. w*256+255]
  {
    int wave = tid >> 6, lane = tid & 63;
    const float* pw = pmax + wave * 256;
    float v = fmaxf(fmaxf(pw[lane], pw[lane + 64]),
                    fmaxf(pw[lane + 128], pw[lane + 192]));
    #pragma unroll
    for (int o = 32; o > 0; o >>= 1) v = fmaxf(v, __shfl_xor(v, o, 64));
    if (lane == 0) lmax[wave] = v;
  }
  __syncthreads();
  int q = blockIdx.x * TPB + tid;              // one quad per thread
  int idx0 = q * 4;
  int b = idx0 / S;
  float rmax_p = sqrtf(lmax[b]);
  float rmax_t = sqrtf(lmax[2 + b]);
  float4 dp4 = ((const float4*)d2)[q];
  float4 dt4 = ((const float4*)(d2 + NBS))[q];
  unsigned spw = (skel[idx0 >> 5] >> (idx0 & 31)) & 0xFu;
  unsigned stw = (skel[(NBS + idx0) >> 5] >> (idx0 & 31)) & 0xFu;
  const float* dp = &dp4.x;
  const float* dt = &dt4.x;
  double acc[4] = {0.0, 0.0, 0.0, 0.0};
  #pragma unroll
  for (int s = 0; s < 4; ++s) {
    float dist_p = sqrtf(dp[s]);
    float dist_t = sqrtf(dt[s]);
    bool sp = (spw >> s) & 1u;
    bool st = (stw >> s) & 1u;
    float q_vp = (rmax_p > 0.0f) ? dist_p / rmax_p : dist_p;
    float q_vl = (rmax_t > 0.0f) ? dist_t / rmax_t : dist_t;
    float q_spvp = sp ? q_vp : 0.0f;
    float q_slvl = st ? q_vl : 0.0f;
    float q_sp = sp ? (1.0f + EPSf) / (q_spvp * q_spvp + EPSf) : 0.0f;
    float q_sl = st ? (1.0f + EPSf) / (q_slvl * q_slvl + EPSf) : 0.0f;
    acc[0] += (double)(q_sp * q_vl);
    acc[1] += (double)(((q_spvp != 0.0f) && (q_slvl == 0.0f)) ? q_spvp * q_sp
                                                              : q_slvl * q_sp);
    acc[2] += (double)(q_sl * q_vp);
    acc[3] += (double)(((q_slvl != 0.0f) && (q_spvp == 0.0f)) ? q_slvl * q_sl
                                                              : q_spvp * q_sl);
  }
  #pragma unroll
  for (int k = 0; k < 4; ++k)
    #pragma unroll
    for (int o = 32; o > 0; o >>= 1)
      acc[k] += __shfl_xor(acc[k], o, 64);
  if ((tid & 63) == 0) {
    #pragma unroll
    for (int k = 0; k < 4; ++k) ldsd[tid >> 6][k] = acc[k];
  }
  __syncthreads();
  if (tid == 0) {
    #pragma unroll
    for (int k = 0; k < 4; ++k)
      ps[blockIdx.x * 4 + k] = ldsd[0][k] + ldsd[1][k] + ldsd[2][k] + ldsd[3][k];
  }
}

// ---- final: reduce 1152x4 partials, compute loss (1 block) ----
__global__ __launch_bounds__(TPB) void k_final(const double* __restrict__ ps,
                                               float* __restrict__ out) {
  __shared__ double ldsd[4][4];
  int tid = threadIdx.x;
  double s[4] = {0.0, 0.0, 0.0, 0.0};
  for (int i = tid; i < BLK_SUMS; i += TPB) {
    s[0] += ps[i * 4 + 0];
    s[1] += ps[i * 4 + 1];
    s[2] += ps[i * 4 + 2];
    s[3] += ps[i * 4 + 3];
  }
  #pragma unroll
  for (int k = 0; k < 4; ++k)
    #pragma unroll
    for (int o = 32; o > 0; o >>= 1)
      s[k] += __shfl_xor(s[k], o, 64);
  if ((tid & 63) == 0) {
    #pragma unroll
    for (int k = 0; k < 4; ++k) ldsd[tid >> 6][k] = s[k];
  }
  __syncthreads();
  if (tid == 0) {
    double tot[4];
    #pragma unroll
    for (int k = 0; k < 4; ++k)
      tot[k] = ldsd[0][k] + ldsd[1][k] + ldsd[2][k] + ldsd[3][k];
    double wp = (tot[0] + 1.0) / (tot[1] + 1.0);
    double ws = (tot[2] + 1.0) / (tot[3] + 1.0);
    out[0] = (float)(1.0 - 2.0 * (wp * ws) / (wp + ws));
  }
}

} // namespace

extern "C" void kernel_launch(void* const* d_in, const int* in_sizes, int n_in,
                              void* d_out, int out_size, void* d_ws, size_t ws_size,
                              hipStream_t stream) {
  (void)in_sizes; (void)n_in; (void)out_size; (void)ws_size;
  const float* logits = (const float*)d_in[0];   // [B,2,D,H,W] f32
  const int* labels   = (const int*)d_in[1];     // [B,1,D,H,W] i32
  float* out = (float*)d_out;

  float* D2 = (float*)d_ws;                  // edt0 output
  float* EF = D2 + NT;                       // edt12 output (final d2)
  unsigned* MB    = (unsigned*)(EF + NT);    // pristine masks
  unsigned* XB    = MB + NTW;
  unsigned* EB    = XB + NTW;
  unsigned* SKELB = EB + NTW;
  float* PMAX  = (float*)(SKELB + NTW);      // 1024 per-quarter-plane d2 maxes
  double* PS   = (double*)(PMAX + 1024);     // 1152x4 doubles (8B-aligned)

  dim3 blk(TPB);

  k_binarize<<<BLK_NBS, blk, 0, stream>>>(logits, labels, MB);

  // skeleton: 11 updates = 4 + 4 + 3 (3 launches, 1024 blocks each)
  k_skel<4><<<1024, blk, 0, stream>>>(MB, XB, SKELB, 1);
  k_skel<4><<<1024, blk, 0, stream>>>(XB, EB, SKELB, 0);
  k_skel<3><<<1024, blk, 0, stream>>>(EB, XB, SKELB, 0);

  // exact EDT: pass0, then fused pass1+pass2 (+pmax), 1024 blocks
  k_edt0<<<BLK_EDT0, blk, 0, stream>>>(MB, D2);
  k_edt12<<<1024, blk, 0, stream>>>(D2, EF, SKELB, PMAX);

  // weighted sums (plain partial stores) + tiny final reduce
  k_sums<<<BLK_SUMS, blk, 0, stream>>>(EF, SKELB, PMAX, PS);
  k_final<<<1, blk, 0, stream>>>(PS, out);
}

// Round 11
// 140.760 us; speedup vs baseline: 8.8886x; 1.0030x over previous
//
#include <hip/hip_runtime.h>

namespace {

constexpr int Bn = 2;
constexpr int Dn = 64;
constexpr int Hn = 96;
constexpr int Wn = 96;
constexpr int HW = Hn * Wn;          // 9216
constexpr int S  = Dn * HW;          // 589824 per (vol,batch) slab
constexpr int NBS = Bn * S;          // 1179648
constexpr int NT  = 2 * NBS;         // 2359296 (slabs: predB0,predB1,truthB0,truthB1)
constexpr int WPR = Wn / 32;         // 3 words per x-row
constexpr int WPP = HW / 32;         // 288 words per z-plane
constexpr int WPS = S / 32;          // 18432 words per slab
constexpr int NTW = NT / 32;         // 73728 packed words
constexpr float INFD = 1e12f;
constexpr float EPSf = 1e-7f;
constexpr int BLK_SUMS = NBS / 4 / 256;   // 1152 (one quad per thread)

// ---- fused binarize + EDT z-pass: block = one slab x 32 columns x all z ----
// Binarize into LDS bit-words (ballot), write MB once, then z min-conv from
// LDS bits. Arithmetic identical to the R5-verified k_binarize + k_edt0.
__global__ __launch_bounds__(256) void k_bin_edt0(const float* __restrict__ logits,
                                                  const int* __restrict__ labels,
                                                  unsigned* __restrict__ Mb,
                                                  float* __restrict__ D2) {
  __shared__ unsigned bits[64];                // one word per z
  int slab = blockIdx.x / 288;                 // 1152 blocks = 4 slabs x 288 groups
  int cg = blockIdx.x - slab * 288;            // 32-column group
  int c0 = cg * 32;
  int tid = threadIdx.x;
  int lane = tid & 63;
  // binarize: 64 z x 32 cols = 2048 voxels, 8 per thread; wave = 2 z-rows
  for (int t = tid; t < 2048; t += 256) {
    int zz = t >> 5;
    int col = t & 31;
    int s = zz * HW + c0 + col;
    bool v;
    if (slab < 2) {
      float l0 = logits[(slab * 2 + 0) * S + s];
      float l1 = logits[(slab * 2 + 1) * S + s];
      v = l1 > l0;                             // softmax(p1)>0.5 <=> l1>l0
    } else {
      v = labels[(slab - 2) * S + s] > 0;
    }
    unsigned long long m = __ballot(v);
    if (lane == 0) {
      unsigned w = (unsigned)m;
      bits[zz] = w;
      Mb[slab * WPS + zz * WPP + cg] = w;
    } else if (lane == 32) {
      unsigned w = (unsigned)(m >> 32);
      bits[zz] = w;
      Mb[slab * WPS + zz * WPP + cg] = w;
    }
  }
  __syncthreads();
  // z-EDT: 32 cols x 8 chunks = 256 tasks (perfect balance)
  int col = tid & 31;
  int chunk = tid >> 5;
  int i0 = chunk * 8;
  float best[8];
  #pragma unroll
  for (int s = 0; s < 8; ++s) best[s] = 3.4e38f;
  float db = (float)i0;
  #pragma unroll 4
  for (int j = 0; j < Dn; ++j) {
    float f = ((bits[j] >> col) & 1u) ? INFD : 0.0f;
    #pragma unroll
    for (int s = 0; s < 8; ++s) {
      float d = db + (float)s;
      best[s] = fminf(best[s], fmaf(d, d, f));
    }
    db -= 1.0f;
  }
  float* o = D2 + slab * S + c0 + col;
  #pragma unroll
  for (int s = 0; s < 8; ++s) o[(i0 + s) * HW] = best[s];
}

// ---- full 11-update skeleton in ONE kernel, quarter-plane per block ----
// Level 0 = X (volume-OOB halo = 1s); level k = erode(level k-1), ping-pong
// through two LDS buffers. skel word = OR_k [ center(L_{k-1}) & ~dil3(L_k) ],
// accumulated in a register (thread t<72 owns word t). dil3 done separably:
// S = OR_(dz,dy) of 9 words, then x-dilate of S via Sbuf neighbors.
// Halo-superset correctness: identical algebra to R8/R9-verified k_skel chain.
__global__ __launch_bounds__(256) void k_skel11(const unsigned* __restrict__ x,
                                                unsigned* __restrict__ skel) {
  __shared__ unsigned bufA[3600];              // max even level (L0: 25x48x3)
  __shared__ unsigned bufB[3174];              // max odd level (L1: 23x46x3)
  __shared__ unsigned Sbuf[72];
  int slab = blockIdx.x >> 8;                  // 1024 = slab(4) x z(64) x q(4)
  int z = (blockIdx.x >> 2) & 63;
  int y0 = (blockIdx.x & 3) * 24;
  int tid = threadIdx.x;
  const unsigned* xs = x + slab * WPS;
  // load L0: planes z-12..z+12, rows y0-12..y0+35
  for (int t = tid; t < 25 * 48 * 3; t += 256) {
    int p = t / 144;
    int rem = t - p * 144;
    int r = rem / 3;
    int wx = rem - r * 3;
    int zz = z - 12 + p, yy = y0 - 12 + r;
    bufA[t] = (zz >= 0 && zz < Dn && yy >= 0 && yy < Hn)
                ? xs[zz * WPP + yy * WPR + wx] : 0xFFFFFFFFu;
  }
  __syncthreads();
  unsigned skreg = 0u;                         // valid for tid < 72
  int ro = tid / 3, wxo = tid - ro * 3;
  int yyo = y0 + ro;
  #pragma unroll
  for (int k = 1; k <= 11; ++k) {
    unsigned* src = (k & 1) ? bufA : bufB;     // level k-1
    unsigned* dst = (k & 1) ? bufB : bufA;     // level k
    const int Rs = 50 - 2 * k;                 // rows of level k-1
    const int Pd = 25 - 2 * k, Rd = 48 - 2 * k;
    const int ps = Rs * 3;
    // erode level k
    for (int t = tid; t < Pd * Rd * 3; t += 256) {
      int p = t / (Rd * 3);
      int rem = t - p * (Rd * 3);
      int r = rem / 3;
      int wx = rem - r * 3;
      int ci = ((p + 1) * Rs + (r + 1)) * 3 + wx;
      unsigned v = src[ci];
      unsigned l = (v << 1) | (wx > 0 ? (src[ci - 1] >> 31) : 1u);
      unsigned rr = (v >> 1) | (wx < 2 ? (src[ci + 1] << 31) : 0x80000000u);
      dst[t] = v & l & rr & src[ci - 3] & src[ci + 3] & src[ci - ps] & src[ci + ps];
    }
    __syncthreads();
    // S = OR over (dz,dy) of level-k words (z/y volume bounds -> skip = pad 0)
    if (tid < 72) {
      const int pc = 12 - k;                   // center plane of level k
      const int rb = ro + 12 - k;              // tile row in level k coords
      unsigned s = 0u;
      #pragma unroll
      for (int dz = -1; dz <= 1; ++dz) {
        if (z + dz < 0 || z + dz >= Dn) continue;
        #pragma unroll
        for (int dy = -1; dy <= 1; ++dy) {
          if (yyo + dy < 0 || yyo + dy >= Hn) continue;
          s |= dst[((pc + dz) * Rd + (rb + dy)) * 3 + wxo];
        }
      }
      Sbuf[tid] = s;
    }
    __syncthreads();
    if (tid < 72) {
      unsigned s = Sbuf[tid];
      unsigned pw = (wxo > 0) ? Sbuf[tid - 1] : 0u;
      unsigned nw = (wxo < 2) ? Sbuf[tid + 1] : 0u;
      unsigned acc = s | ((s << 1) | (pw >> 31)) | ((s >> 1) | (nw << 31));
      unsigned prevC = src[((13 - k) * Rs + (ro + 13 - k)) * 3 + wxo];
      skreg |= prevC & ~acc;                   // X_{k-1} & ~dil3(erode(X_{k-1}))
    }
    __syncthreads();                           // next erode overwrites src
  }
  if (tid < 72) {
    int gi = slab * WPS + z * WPP + yyo * WPR + wxo;
    skel[gi] = skreg;
  }
}

// ---- fused EDT pass1(y)+pass2(x), quarter-plane, 192 threads (balanced) ----
// 192 tasks per pass = 3 full waves, one round each. Bit-exact: every
// candidate value is exact in f32 (ints < 2^24; 1e12 absorbs +9216 exactly).
__global__ __launch_bounds__(192) void k_edt12(const float* __restrict__ D2,
                                               float* __restrict__ EF,
                                               const unsigned* __restrict__ skel,
                                               float* __restrict__ pmax) {
  __shared__ float Bh[24 * 97];                // pass1 quarter, padded
  __shared__ float ldsf[3];
  int slab = blockIdx.x >> 8;                  // 1024 = slab(4) x z(64) x q(4)
  int zz = (blockIdx.x >> 2) & 63;
  int y0 = (blockIdx.x & 3) * 24;
  int tid = threadIdx.x;
  int pb = slab * S + zz * HW;
  // pass1: y min-conv; task = (col, 12-output chunk)
  {
    int xx = tid % 96;
    int c = tid / 96;                          // 0..1
    float best[12];
    #pragma unroll
    for (int s = 0; s < 12; ++s) best[s] = 3.4e38f;
    float db = (float)(y0 + c * 12);
    #pragma unroll 4
    for (int j = 0; j < Hn; ++j) {
      float f = D2[pb + j * 96 + xx];
      #pragma unroll
      for (int s = 0; s < 12; ++s) {
        float d = db + (float)s;
        best[s] = fminf(best[s], fmaf(d, d, f));
      }
      db -= 1.0f;
    }
    #pragma unroll
    for (int s = 0; s < 12; ++s) Bh[(c * 12 + s) * 97 + xx] = best[s];
  }
  __syncthreads();
  // pass2: x min-conv; task = (row, 12-output chunk); write EF + masked max
  float m = 0.0f;
  {
    int r = tid >> 3;                          // 0..23
    int chunk = tid & 7;                       // 0..7
    int i0 = chunk * 12;
    float best[12];
    #pragma unroll
    for (int s = 0; s < 12; ++s) best[s] = 3.4e38f;
    float db = (float)i0;
    #pragma unroll 4
    for (int j = 0; j < Wn; ++j) {
      float f = Bh[r * 97 + j];
      #pragma unroll
      for (int s = 0; s < 12; ++s) {
        float d = db + (float)s;
        best[s] = fminf(best[s], fmaf(d, d, f));
      }
      db -= 1.0f;
    }
    int gb = pb + (y0 + r) * 96 + i0;
    ((float4*)(EF + gb))[0] = make_float4(best[0], best[1], best[2], best[3]);
    ((float4*)(EF + gb))[1] = make_float4(best[4], best[5], best[6], best[7]);
    ((float4*)(EF + gb))[2] = make_float4(best[8], best[9], best[10], best[11]);
    int sh = gb & 31;
    unsigned w0 = skel[gb >> 5];
    unsigned w1 = (sh + 11 > 31) ? skel[(gb >> 5) + 1] : 0u;  // straddle only
    unsigned long long wv = ((unsigned long long)w1 << 32) | (unsigned long long)w0;
    unsigned bitsv = (unsigned)(wv >> sh);
    #pragma unroll
    for (int s = 0; s < 12; ++s)
      if ((bitsv >> s) & 1u) m = fmaxf(m, best[s]);
  }
  #pragma unroll
  for (int o = 32; o > 0; o >>= 1) m = fmaxf(m, __shfl_xor(m, o, 64));
  if ((tid & 63) == 0) ldsf[tid >> 6] = m;
  __syncthreads();
  if (tid == 0)
    pmax[blockIdx.x] = fmaxf(fmaxf(ldsf[0], ldsf[1]), ldsf[2]);
}

// ---- sums: redundant rmax reduce + per-quad terms -> plain partial stores ----
__global__ __launch_bounds__(256) void k_sums(const float* __restrict__ d2,
                                              const unsigned* __restrict__ skel,
                                              const float* __restrict__ pmax,
                                              double* __restrict__ ps) {
  __shared__ float lmax[4];
  __shared__ double ldsd[4][4];
  int tid = threadIdx.x;
  {
    int wave = tid >> 6, lane = tid & 63;
    const float* pw = pmax + wave * 256;
    float v = fmaxf(fmaxf(pw[lane], pw[lane + 64]),
                    fmaxf(pw[lane + 128], pw[lane + 192]));
    #pragma unroll
    for (int o = 32; o > 0; o >>= 1) v = fmaxf(v, __shfl_xor(v, o, 64));
    if (lane == 0) lmax[wave] = v;
  }
  __syncthreads();
  int q = blockIdx.x * 256 + tid;              // one quad per thread
  int idx0 = q * 4;
  int b = idx0 / S;
  float rmax_p = sqrtf(lmax[b]);
  float rmax_t = sqrtf(lmax[2 + b]);
  float4 dp4 = ((const float4*)d2)[q];
  float4 dt4 = ((const float4*)(d2 + NBS))[q];
  unsigned spw = (skel[idx0 >> 5] >> (idx0 & 31)) & 0xFu;
  unsigned stw = (skel[(NBS + idx0) >> 5] >> (idx0 & 31)) & 0xFu;
  const float* dp = &dp4.x;
  const float* dt = &dt4.x;
  double acc[4] = {0.0, 0.0, 0.0, 0.0};
  #pragma unroll
  for (int s = 0; s < 4; ++s) {
    float dist_p = sqrtf(dp[s]);
    float dist_t = sqrtf(dt[s]);
    bool sp = (spw >> s) & 1u;
    bool st = (stw >> s) & 1u;
    float q_vp = (rmax_p > 0.0f) ? dist_p / rmax_p : dist_p;
    float q_vl = (rmax_t > 0.0f) ? dist_t / rmax_t : dist_t;
    float q_spvp = sp ? q_vp : 0.0f;
    float q_slvl = st ? q_vl : 0.0f;
    float q_sp = sp ? (1.0f + EPSf) / (q_spvp * q_spvp + EPSf) : 0.0f;
    float q_sl = st ? (1.0f + EPSf) / (q_slvl * q_slvl + EPSf) : 0.0f;
    acc[0] += (double)(q_sp * q_vl);
    acc[1] += (double)(((q_spvp != 0.0f) && (q_slvl == 0.0f)) ? q_spvp * q_sp
                                                              : q_slvl * q_sp);
    acc[2] += (double)(q_sl * q_vp);
    acc[3] += (double)(((q_slvl != 0.0f) && (q_spvp == 0.0f)) ? q_slvl * q_sl
                                                              : q_spvp * q_sl);
  }
  #pragma unroll
  for (int k = 0; k < 4; ++k)
    #pragma unroll
    for (int o = 32; o > 0; o >>= 1)
      acc[k] += __shfl_xor(acc[k], o, 64);
  if ((tid & 63) == 0) {
    #pragma unroll
    for (int k = 0; k < 4; ++k) ldsd[tid >> 6][k] = acc[k];
  }
  __syncthreads();
  if (tid == 0) {
    #pragma unroll
    for (int k = 0; k < 4; ++k)
      ps[blockIdx.x * 4 + k] = ldsd[0][k] + ldsd[1][k] + ldsd[2][k] + ldsd[3][k];
  }
}

// ---- final: reduce 1152x4 partials, compute loss (1 block) ----
__global__ __launch_bounds__(256) void k_final(const double* __restrict__ ps,
                                               float* __restrict__ out) {
  __shared__ double ldsd[4][4];
  int tid = threadIdx.x;
  double s[4] = {0.0, 0.0, 0.0, 0.0};
  for (int i = tid; i < BLK_SUMS; i += 256) {
    s[0] += ps[i * 4 + 0];
    s[1] += ps[i * 4 + 1];
    s[2] += ps[i * 4 + 2];
    s[3] += ps[i * 4 + 3];
  }
  #pragma unroll
  for (int k = 0; k < 4; ++k)
    #pragma unroll
    for (int o = 32; o > 0; o >>= 1)
      s[k] += __shfl_xor(s[k], o, 64);
  if ((tid & 63) == 0) {
    #pragma unroll
    for (int k = 0; k < 4; ++k) ldsd[tid >> 6][k] = s[k];
  }
  __syncthreads();
  if (tid == 0) {
    double tot[4];
    #pragma unroll
    for (int k = 0; k < 4; ++k)
      tot[k] = ldsd[0][k] + ldsd[1][k] + ldsd[2][k] + ldsd[3][k];
    double wp = (tot[0] + 1.0) / (tot[1] + 1.0);
    double ws = (tot[2] + 1.0) / (tot[3] + 1.0);
    out[0] = (float)(1.0 - 2.0 * (wp * ws) / (wp + ws));
  }
}

} // namespace

extern "C" void kernel_launch(void* const* d_in, const int* in_sizes, int n_in,
                              void* d_out, int out_size, void* d_ws, size_t ws_size,
                              hipStream_t stream) {
  (void)in_sizes; (void)n_in; (void)out_size; (void)ws_size;
  const float* logits = (const float*)d_in[0];   // [B,2,D,H,W] f32
  const int* labels   = (const int*)d_in[1];     // [B,1,D,H,W] i32
  float* out = (float*)d_out;

  float* D2 = (float*)d_ws;                  // edt0 output
  float* EF = D2 + NT;                       // edt12 output (final d2)
  unsigned* MB    = (unsigned*)(EF + NT);    // masks
  unsigned* SKELB = MB + NTW;
  float* PMAX  = (float*)(SKELB + NTW);      // 1024 per-quarter-plane d2 maxes
  double* PS   = (double*)(PMAX + 1024);     // 1152x4 doubles (8B-aligned)

  k_bin_edt0<<<1152, 256, 0, stream>>>(logits, labels, MB, D2);
  k_skel11<<<1024, 256, 0, stream>>>(MB, SKELB);
  k_edt12<<<1024, 192, 0, stream>>>(D2, EF, SKELB, PMAX);
  k_sums<<<1152, 256, 0, stream>>>(EF, SKELB, PMAX, PS);
  k_final<<<1, 256, 0, stream>>>(PS, out);
}

// Round 12
// 136.455 us; speedup vs baseline: 9.1691x; 1.0316x over previous
//
#include <hip/hip_runtime.h>

namespace {

constexpr int Bn = 2;
constexpr int Dn = 64;
constexpr int Hn = 96;
constexpr int Wn = 96;
constexpr int HW = Hn * Wn;          // 9216
constexpr int S  = Dn * HW;          // 589824 per (vol,batch) slab
constexpr int NBS = Bn * S;          // 1179648
constexpr int NT  = 2 * NBS;         // 2359296 (slabs: predB0,predB1,truthB0,truthB1)
constexpr int WPR = Wn / 32;         // 3 words per x-row
constexpr int WPP = HW / 32;         // 288 words per z-plane
constexpr int WPS = S / 32;          // 18432 words per slab
constexpr int NTW = NT / 32;         // 73728 packed words
constexpr float EPSf = 1e-7f;
constexpr int BLK_SUMS = NBS / 4 / 256;   // 1152 (one quad per thread)
// RN(1e12) in f32 — the exact all-foreground EDT value the reference produces
#define BIGF 1e12f

// ---- fused binarize + EDT z-pass (bit-scan: d = dist to nearest zero bit) ----
// out[i] = d*d (exact int) or RN(1e12) if column all-foreground — bit-identical
// to the brute-force min_j (i-j)^2 + {0,1e12} (d^2 <= 3969 exact; BIG absorbs).
__global__ __launch_bounds__(256) void k_bin_edt0(const float* __restrict__ logits,
                                                  const int* __restrict__ labels,
                                                  unsigned* __restrict__ Mb,
                                                  float* __restrict__ D2) {
  __shared__ unsigned bits[64];                // one word per z (32 cols)
  __shared__ unsigned zlo[32], zhi[32];        // per-col zero masks
  int slab = blockIdx.x / 288;                 // 1152 blocks = 4 slabs x 288 groups
  int cg = blockIdx.x - slab * 288;            // 32-column group
  int c0 = cg * 32;
  int tid = threadIdx.x;
  int lane = tid & 63;
  // binarize: 64 z x 32 cols, ballot-packed (identical to R11)
  for (int t = tid; t < 2048; t += 256) {
    int zz = t >> 5;
    int col = t & 31;
    int s = zz * HW + c0 + col;
    bool v;
    if (slab < 2) {
      float l0 = logits[(slab * 2 + 0) * S + s];
      float l1 = logits[(slab * 2 + 1) * S + s];
      v = l1 > l0;                             // softmax(p1)>0.5 <=> l1>l0
    } else {
      v = labels[(slab - 2) * S + s] > 0;
    }
    unsigned long long m = __ballot(v);
    if (lane == 0) {
      unsigned w = (unsigned)m;
      bits[zz] = w;
      Mb[slab * WPS + zz * WPP + cg] = w;
    } else if (lane == 32) {
      unsigned w = (unsigned)(m >> 32);
      bits[zz] = w;
      Mb[slab * WPS + zz * WPP + cg] = w;
    }
  }
  __syncthreads();
  // build per-column 64-bit ZERO masks (bit j set <=> voxel background)
  if (tid < 64) {
    int col = tid & 31;
    int base = (tid < 32) ? 0 : 32;
    unsigned zw = 0u;
    #pragma unroll
    for (int j = 0; j < 32; ++j)
      zw |= (((bits[base + j] >> col) & 1u) ^ 1u) << j;
    if (tid < 32) zlo[col] = zw; else zhi[col] = zw;
  }
  __syncthreads();
  // z-EDT via bit scan: 32 cols x 8 chunks = 256 tasks
  int col = tid & 31;
  int chunk = tid >> 5;
  int i0 = chunk * 8;
  unsigned long long Z = ((unsigned long long)zhi[col] << 32) | (unsigned long long)zlo[col];
  float* o = D2 + slab * S + c0 + col;
  #pragma unroll
  for (int s = 0; s < 8; ++s) {
    int i = i0 + s;
    unsigned long long below = Z & ((2ull << i) - 1ull);   // bits 0..i (i=63 ok)
    unsigned long long above = Z >> i;                     // bits i..63
    float outv;
    if (below | above) {
      int ddn = below ? (i - (63 - __builtin_clzll(below))) : 99;
      int dup = above ? __builtin_ctzll(above) : 99;
      int d = ddn < dup ? ddn : dup;
      outv = (float)(d * d);
    } else {
      outv = BIGF;
    }
    o[i * HW] = outv;
  }
}

// ---- full 11-update skeleton in ONE kernel, quarter-plane per block ----
// (unchanged from R11 — verified absmax 0)
__global__ __launch_bounds__(256) void k_skel11(const unsigned* __restrict__ x,
                                                unsigned* __restrict__ skel) {
  __shared__ unsigned bufA[3600];              // max even level (L0: 25x48x3)
  __shared__ unsigned bufB[3174];              // max odd level (L1: 23x46x3)
  __shared__ unsigned Sbuf[72];
  int slab = blockIdx.x >> 8;                  // 1024 = slab(4) x z(64) x q(4)
  int z = (blockIdx.x >> 2) & 63;
  int y0 = (blockIdx.x & 3) * 24;
  int tid = threadIdx.x;
  const unsigned* xs = x + slab * WPS;
  for (int t = tid; t < 25 * 48 * 3; t += 256) {
    int p = t / 144;
    int rem = t - p * 144;
    int r = rem / 3;
    int wx = rem - r * 3;
    int zz = z - 12 + p, yy = y0 - 12 + r;
    bufA[t] = (zz >= 0 && zz < Dn && yy >= 0 && yy < Hn)
                ? xs[zz * WPP + yy * WPR + wx] : 0xFFFFFFFFu;
  }
  __syncthreads();
  unsigned skreg = 0u;                         // valid for tid < 72
  int ro = tid / 3, wxo = tid - ro * 3;
  int yyo = y0 + ro;
  #pragma unroll
  for (int k = 1; k <= 11; ++k) {
    unsigned* src = (k & 1) ? bufA : bufB;     // level k-1
    unsigned* dst = (k & 1) ? bufB : bufA;     // level k
    const int Rs = 50 - 2 * k;
    const int Pd = 25 - 2 * k, Rd = 48 - 2 * k;
    const int ps = Rs * 3;
    for (int t = tid; t < Pd * Rd * 3; t += 256) {
      int p = t / (Rd * 3);
      int rem = t - p * (Rd * 3);
      int r = rem / 3;
      int wx = rem - r * 3;
      int ci = ((p + 1) * Rs + (r + 1)) * 3 + wx;
      unsigned v = src[ci];
      unsigned l = (v << 1) | (wx > 0 ? (src[ci - 1] >> 31) : 1u);
      unsigned rr = (v >> 1) | (wx < 2 ? (src[ci + 1] << 31) : 0x80000000u);
      dst[t] = v & l & rr & src[ci - 3] & src[ci + 3] & src[ci - ps] & src[ci + ps];
    }
    __syncthreads();
    if (tid < 72) {
      const int pc = 12 - k;
      const int rb = ro + 12 - k;
      unsigned s = 0u;
      #pragma unroll
      for (int dz = -1; dz <= 1; ++dz) {
        if (z + dz < 0 || z + dz >= Dn) continue;
        #pragma unroll
        for (int dy = -1; dy <= 1; ++dy) {
          if (yyo + dy < 0 || yyo + dy >= Hn) continue;
          s |= dst[((pc + dz) * Rd + (rb + dy)) * 3 + wxo];
        }
      }
      Sbuf[tid] = s;
    }
    __syncthreads();
    if (tid < 72) {
      unsigned s = Sbuf[tid];
      unsigned pw = (wxo > 0) ? Sbuf[tid - 1] : 0u;
      unsigned nw = (wxo < 2) ? Sbuf[tid + 1] : 0u;
      unsigned acc = s | ((s << 1) | (pw >> 31)) | ((s >> 1) | (nw << 31));
      unsigned prevC = src[((13 - k) * Rs + (ro + 13 - k)) * 3 + wxo];
      skreg |= prevC & ~acc;
    }
    __syncthreads();
  }
  if (tid < 72) {
    int gi = slab * WPS + z * WPP + yyo * WPR + wxo;
    skel[gi] = skreg;
  }
}

// ---- fused EDT pass1(y)+pass2(x), g-trick (2 inner ops), 192 threads ----
// out[y] = y^2 + min_j (j^2 - 2yj + f[j]); all small candidates exact ints so
// the -y^2 shift preserves argmin and fmaf(y,y,min) reconstructs the original
// value bit-exactly; BIG (1e12) absorbs +-18050 at ulp 65536 identically.
__global__ __launch_bounds__(192) void k_edt12(const float* __restrict__ D2,
                                               float* __restrict__ EF,
                                               const unsigned* __restrict__ skel,
                                               float* __restrict__ pmax) {
  __shared__ float Bh[24 * 97];                // pass1 quarter, padded
  __shared__ float ldsf[3];
  int slab = blockIdx.x >> 8;                  // 1024 = slab(4) x z(64) x q(4)
  int zz = (blockIdx.x >> 2) & 63;
  int y0 = (blockIdx.x & 3) * 24;
  int tid = threadIdx.x;
  int pb = slab * S + zz * HW;
  // pass1: y min-conv; task = (col, 12-output chunk)
  {
    int xx = tid % 96;
    int c = tid / 96;                          // 0..1
    int ybase = y0 + c * 12;
    float m2[12];
    #pragma unroll
    for (int s = 0; s < 12; ++s) m2[s] = -2.0f * (float)(ybase + s);
    float best[12];
    #pragma unroll
    for (int s = 0; s < 12; ++s) best[s] = 3.4e38f;
    float jf = 0.0f;
    #pragma unroll 2
    for (int j = 0; j < Hn; ++j) {
      float f = D2[pb + j * 96 + xx];
      float g = fmaf(jf, jf, f);               // j^2 + f (exact / BIG-absorbed)
      #pragma unroll
      for (int s = 0; s < 12; ++s)
        best[s] = fminf(best[s], fmaf(m2[s], jf, g));
      jf += 1.0f;
    }
    #pragma unroll
    for (int s = 0; s < 12; ++s) {
      float yf = (float)(ybase + s);
      Bh[(c * 12 + s) * 97 + xx] = fmaf(yf, yf, best[s]);
    }
  }
  __syncthreads();
  // pass2: x min-conv; task = (row, 12-output chunk); write EF + masked max
  float m = 0.0f;
  {
    int r = tid >> 3;                          // 0..23
    int chunk = tid & 7;                       // 0..7
    int i0 = chunk * 12;
    float m2[12];
    #pragma unroll
    for (int s = 0; s < 12; ++s) m2[s] = -2.0f * (float)(i0 + s);
    float best[12];
    #pragma unroll
    for (int s = 0; s < 12; ++s) best[s] = 3.4e38f;
    float jf = 0.0f;
    #pragma unroll 2
    for (int j = 0; j < Wn; ++j) {
      float f = Bh[r * 97 + j];
      float g = fmaf(jf, jf, f);
      #pragma unroll
      for (int s = 0; s < 12; ++s)
        best[s] = fminf(best[s], fmaf(m2[s], jf, g));
      jf += 1.0f;
    }
    float outv[12];
    #pragma unroll
    for (int s = 0; s < 12; ++s) {
      float xf = (float)(i0 + s);
      outv[s] = fmaf(xf, xf, best[s]);
    }
    int gb = pb + (y0 + r) * 96 + i0;
    ((float4*)(EF + gb))[0] = make_float4(outv[0], outv[1], outv[2], outv[3]);
    ((float4*)(EF + gb))[1] = make_float4(outv[4], outv[5], outv[6], outv[7]);
    ((float4*)(EF + gb))[2] = make_float4(outv[8], outv[9], outv[10], outv[11]);
    int sh = gb & 31;
    unsigned w0 = skel[gb >> 5];
    unsigned w1 = (sh + 11 > 31) ? skel[(gb >> 5) + 1] : 0u;
    unsigned long long wv = ((unsigned long long)w1 << 32) | (unsigned long long)w0;
    unsigned bitsv = (unsigned)(wv >> sh);
    #pragma unroll
    for (int s = 0; s < 12; ++s)
      if ((bitsv >> s) & 1u) m = fmaxf(m, outv[s]);
  }
  #pragma unroll
  for (int o = 32; o > 0; o >>= 1) m = fmaxf(m, __shfl_xor(m, o, 64));
  if ((tid & 63) == 0) ldsf[tid >> 6] = m;
  __syncthreads();
  if (tid == 0)
    pmax[blockIdx.x] = fmaxf(fmaxf(ldsf[0], ldsf[1]), ldsf[2]);
}

// ---- sums: redundant rmax reduce + per-quad terms -> plain partial stores ----
__global__ __launch_bounds__(256) void k_sums(const float* __restrict__ d2,
                                              const unsigned* __restrict__ skel,
                                              const float* __restrict__ pmax,
                                              double* __restrict__ ps) {
  __shared__ float lmax[4];
  __shared__ double ldsd[4][4];
  int tid = threadIdx.x;
  {
    int wave = tid >> 6, lane = tid & 63;
    const float* pw = pmax + wave * 256;
    float v = fmaxf(fmaxf(pw[lane], pw[lane + 64]),
                    fmaxf(pw[lane + 128], pw[lane + 192]));
    #pragma unroll
    for (int o = 32; o > 0; o >>= 1) v = fmaxf(v, __shfl_xor(v, o, 64));
    if (lane == 0) lmax[wave] = v;
  }
  __syncthreads();
  int q = blockIdx.x * 256 + tid;              // one quad per thread
  int idx0 = q * 4;
  int b = idx0 / S;
  float rmax_p = sqrtf(lmax[b]);
  float rmax_t = sqrtf(lmax[2 + b]);
  float4 dp4 = ((const float4*)d2)[q];
  float4 dt4 = ((const float4*)(d2 + NBS))[q];
  unsigned spw = (skel[idx0 >> 5] >> (idx0 & 31)) & 0xFu;
  unsigned stw = (skel[(NBS + idx0) >> 5] >> (idx0 & 31)) & 0xFu;
  const float* dp = &dp4.x;
  const float* dt = &dt4.x;
  double acc[4] = {0.0, 0.0, 0.0, 0.0};
  #pragma unroll
  for (int s = 0; s < 4; ++s) {
    float dist_p = sqrtf(dp[s]);
    float dist_t = sqrtf(dt[s]);
    bool sp = (spw >> s) & 1u;
    bool st = (stw >> s) & 1u;
    float q_vp = (rmax_p > 0.0f) ? dist_p / rmax_p : dist_p;
    float q_vl = (rmax_t > 0.0f) ? dist_t / rmax_t : dist_t;
    float q_spvp = sp ? q_vp : 0.0f;
    float q_slvl = st ? q_vl : 0.0f;
    float q_sp = sp ? (1.0f + EPSf) / (q_spvp * q_spvp + EPSf) : 0.0f;
    float q_sl = st ? (1.0f + EPSf) / (q_slvl * q_slvl + EPSf) : 0.0f;
    acc[0] += (double)(q_sp * q_vl);
    acc[1] += (double)(((q_spvp != 0.0f) && (q_slvl == 0.0f)) ? q_spvp * q_sp
                                                              : q_slvl * q_sp);
    acc[2] += (double)(q_sl * q_vp);
    acc[3] += (double)(((q_slvl != 0.0f) && (q_spvp == 0.0f)) ? q_slvl * q_sl
                                                              : q_spvp * q_sl);
  }
  #pragma unroll
  for (int k = 0; k < 4; ++k)
    #pragma unroll
    for (int o = 32; o > 0; o >>= 1)
      acc[k] += __shfl_xor(acc[k], o, 64);
  if ((tid & 63) == 0) {
    #pragma unroll
    for (int k = 0; k < 4; ++k) ldsd[tid >> 6][k] = acc[k];
  }
  __syncthreads();
  if (tid == 0) {
    #pragma unroll
    for (int k = 0; k < 4; ++k)
      ps[blockIdx.x * 4 + k] = ldsd[0][k] + ldsd[1][k] + ldsd[2][k] + ldsd[3][k];
  }
}

// ---- final: reduce 1152x4 partials, compute loss (1 block) ----
__global__ __launch_bounds__(256) void k_final(const double* __restrict__ ps,
                                               float* __restrict__ out) {
  __shared__ double ldsd[4][4];
  int tid = threadIdx.x;
  double s[4] = {0.0, 0.0, 0.0, 0.0};
  for (int i = tid; i < BLK_SUMS; i += 256) {
    s[0] += ps[i * 4 + 0];
    s[1] += ps[i * 4 + 1];
    s[2] += ps[i * 4 + 2];
    s[3] += ps[i * 4 + 3];
  }
  #pragma unroll
  for (int k = 0; k < 4; ++k)
    #pragma unroll
    for (int o = 32; o > 0; o >>= 1)
      s[k] += __shfl_xor(s[k], o, 64);
  if ((tid & 63) == 0) {
    #pragma unroll
    for (int k = 0; k < 4; ++k) ldsd[tid >> 6][k] = s[k];
  }
  __syncthreads();
  if (tid == 0) {
    double tot[4];
    #pragma unroll
    for (int k = 0; k < 4; ++k)
      tot[k] = ldsd[0][k] + ldsd[1][k] + ldsd[2][k] + ldsd[3][k];
    double wp = (tot[0] + 1.0) / (tot[1] + 1.0);
    double ws = (tot[2] + 1.0) / (tot[3] + 1.0);
    out[0] = (float)(1.0 - 2.0 * (wp * ws) / (wp + ws));
  }
}

} // namespace

extern "C" void kernel_launch(void* const* d_in, const int* in_sizes, int n_in,
                              void* d_out, int out_size, void* d_ws, size_t ws_size,
                              hipStream_t stream) {
  (void)in_sizes; (void)n_in; (void)out_size; (void)ws_size;
  const float* logits = (const float*)d_in[0];   // [B,2,D,H,W] f32
  const int* labels   = (const int*)d_in[1];     // [B,1,D,H,W] i32
  float* out = (float*)d_out;

  float* D2 = (float*)d_ws;                  // edt0 output
  float* EF = D2 + NT;                       // edt12 output (final d2)
  unsigned* MB    = (unsigned*)(EF + NT);    // masks
  unsigned* SKELB = MB + NTW;
  float* PMAX  = (float*)(SKELB + NTW);      // 1024 per-quarter-plane d2 maxes
  double* PS   = (double*)(PMAX + 1024);     // 1152x4 doubles (8B-aligned)

  k_bin_edt0<<<1152, 256, 0, stream>>>(logits, labels, MB, D2);
  k_skel11<<<1024, 256, 0, stream>>>(MB, SKELB);
  k_edt12<<<1024, 192, 0, stream>>>(D2, EF, SKELB, PMAX);
  k_sums<<<1152, 256, 0, stream>>>(EF, SKELB, PMAX, PS);
  k_final<<<1, 256, 0, stream>>>(PS, out);
}